// Round 2
// baseline (426.212 us; speedup 1.0000x reference)
//
#include <hip/hip_runtime.h>
#include <stdint.h>

// AudioSNN: conv1(1->32,64x32)+spike+pool -> conv2(32->64,32x16)+spike+pool
// -> fc1 -> 25-step LIF recurrence (fc2, fc3). All fp32 (no fp32 MFMA on CDNA4;
// spikes are Heaviside => numerics must stay fp32-faithful).
//
// ws layout:
//   c1   u8  [1024][32][32][16]   16 MB   (pool counts 0..4; c1 float = n/4)
//   xq   u8  [1024][8192]          8 MB   (x_flat counts 0..4)
//   cur3 f32 [1024][256]           1 MB
//   w2t  f32 [256][128]          128 KB   (fc2_w transposed)
//   part f32 [32][1024][256]      32 MB   (fc1 K-split partials)

#define NSTEP 25

__device__ __forceinline__ float lif_update(float mem, float cur) {
#pragma clang fp contract(off)
  // snntorch Leaky, reset_mechanism='subtract': reset from PREVIOUS mem.
  float reset = (mem > 1.0f) ? 1.0f : 0.0f;
  float m = 0.95f * mem;
  m = m + cur;
  m = m - reset;
  return m;
}

// ---------------------------------------------------------------- w2 transpose
__global__ __launch_bounds__(256) void k_w2t(const float* __restrict__ w2,
                                             float* __restrict__ w2t) {
  // w2: [128][256] -> w2t: [256][128]
  const int j = blockIdx.x;    // 128
  const int i = threadIdx.x;   // 256
  w2t[i * 128 + j] = w2[j * 256 + i];
}

// ---------------------------------------------------------------- conv1 fused
__global__ __launch_bounds__(256) void k_conv1(const float* __restrict__ x,
                                               const float* __restrict__ w,
                                               const float* __restrict__ bias,
                                               uint8_t* __restrict__ c1) {
  __shared__ float xin[66 * 34];   // 64x32 + SAME halo, zero padded
  __shared__ float wl[288];
  __shared__ float bl[32];
  const int t = threadIdx.x;
  const int s = blockIdx.x;

  for (int idx = t; idx < 66 * 34; idx += 256) xin[idx] = 0.0f;
  wl[t] = w[t];                       // t<256
  if (t < 32) { wl[256 + t] = w[256 + t]; bl[t] = bias[t]; }
  __syncthreads();

  const float* xs = x + (size_t)s * (64 * 32);
#pragma unroll
  for (int r = 0; r < 2; ++r) {
    int idx = t + r * 256;            // 0..511 -> 64 rows x 8 quads
    int y = idx >> 3, q = idx & 7;
    float4 v = *(const float4*)(xs + y * 32 + q * 4);
    float* dst = &xin[(y + 1) * 34 + q * 4 + 1];
    dst[0] = v.x; dst[1] = v.y; dst[2] = v.z; dst[3] = v.w;
  }
  __syncthreads();

  uint8_t* c1s = c1 + (size_t)s * (32 * 32 * 16);
  for (int rr = 0; rr < 64; ++rr) {
    int idx = rr * 256 + t;           // ch wave-uniform (512 pos per ch)
    int ch = idx >> 9;
    int pos = idx & 511;
    int py = pos >> 4, px = pos & 15;
    const float* wc = &wl[ch * 9];
    float bv = bl[ch];
    float p[4][4];
#pragma unroll
    for (int rw = 0; rw < 4; ++rw) {
      float2 a = *(const float2*)&xin[(2 * py + rw) * 34 + 2 * px];
      float2 b = *(const float2*)&xin[(2 * py + rw) * 34 + 2 * px + 2];
      p[rw][0] = a.x; p[rw][1] = a.y; p[rw][2] = b.x; p[rw][3] = b.y;
    }
    int cnt = 0;
#pragma unroll
    for (int dy = 0; dy < 2; ++dy)
#pragma unroll
      for (int dx = 0; dx < 2; ++dx) {
        float acc = 0.0f;
#pragma unroll
        for (int ky = 0; ky < 3; ++ky)
#pragma unroll
          for (int kx = 0; kx < 3; ++kx)
            acc += wc[ky * 3 + kx] * p[dy + ky][dx + kx];
        float v = acc + bv;
        cnt += (v > 1.0f) ? 1 : 0;
      }
    c1s[ch * 512 + py * 16 + px] = (uint8_t)cnt;
  }
}

// ---------------------------------------------------------------- conv2 fused
// LDS input tile stored as u8 (11.5 KB vs 46 KB f32): occupancy 3 -> ~7 blk/CU.
__global__ __launch_bounds__(256) void k_conv2(const uint8_t* __restrict__ c1,
                                               const float* __restrict__ w,   // [64][32][9]
                                               const float* __restrict__ bias,
                                               uint8_t* __restrict__ xq) {
  // One block = one sample x one row-half (16 conv rows).
  // cin: u8 [c][r(18)][20 bytes]; byte 0 = x=-1 pad, bytes 1..16 = x0..x15,
  // byte 17 = x=16 pad. Stored as 5 dwords per row (rows 4B-aligned).
  __shared__ uint32_t cin[32 * 18 * 5];   // 11520 B
  const int t = threadIdx.x;
  const int s = blockIdx.x >> 1;
  const int half = blockIdx.x & 1;

  for (int idx = t; idx < 32 * 18 * 5; idx += 256) cin[idx] = 0u;
  __syncthreads();

  const uint8_t* c1s = c1 + (size_t)s * (32 * 32 * 16);
  for (int idx = t; idx < 576; idx += 256) {   // 32 c x 18 rows
    int c = idx / 18, r = idx % 18;
    int y = half * 16 + r - 1;
    if (y >= 0 && y < 32) {
      uint4 u = *(const uint4*)(c1s + (c * 32 + y) * 16);
      uint32_t* dst = &cin[(c * 18 + r) * 5];
      dst[0] = u.x << 8;                      // byte0 = 0 (left pad)
      dst[1] = (u.x >> 24) | (u.y << 8);
      dst[2] = (u.y >> 24) | (u.z << 8);
      dst[3] = (u.z >> 24) | (u.w << 8);
      dst[4] = (u.w >> 24);                   // byte17.. = 0 (right pad)
    }
  }
  __syncthreads();

  const int lane = t & 63;
  const int wav = __builtin_amdgcn_readfirstlane(t >> 6);  // wave-uniform
  const int pr = lane >> 3, pc = lane & 7;                 // pooled pos in 8x8
  const int cr = 2 * pr, cc = 2 * pc;
  const int cc4 = cc >> 2;          // dword index within row (0..3)
  const int sh = (cc & 3) * 8;      // 0 or 16 bit shift

  float acc[16][4];
#pragma unroll
  for (int a = 0; a < 16; ++a) {
    acc[a][0] = 0.f; acc[a][1] = 0.f; acc[a][2] = 0.f; acc[a][3] = 0.f;
  }

  for (int c = 0; c < 32; ++c) {
    float p[4][4];
#pragma unroll
    for (int rw = 0; rw < 4; ++rw) {
      const uint32_t* rowp = &cin[(c * 18 + cr + rw) * 5 + cc4];
      uint32_t w0 = rowp[0], w1 = rowp[1];
      uint32_t v = (uint32_t)(((((uint64_t)w1) << 32) | (uint64_t)w0) >> sh);
      p[rw][0] = (float)(v & 0xffu);
      p[rw][1] = (float)((v >> 8) & 0xffu);
      p[rw][2] = (float)((v >> 16) & 0xffu);
      p[rw][3] = (float)(v >> 24);
    }
#pragma unroll
    for (int oci = 0; oci < 16; ++oci) {
      const float* wp = w + (size_t)((wav * 16 + oci) * 32 + c) * 9;  // uniform addr
      float w0 = wp[0], w1 = wp[1], w2 = wp[2], w3 = wp[3], w4 = wp[4],
            w5 = wp[5], w6 = wp[6], w7 = wp[7], w8 = wp[8];
#pragma unroll
      for (int dy = 0; dy < 2; ++dy)
#pragma unroll
        for (int dx = 0; dx < 2; ++dx) {
          float sum = acc[oci][dy * 2 + dx];
          sum += w0 * p[dy + 0][dx + 0];
          sum += w1 * p[dy + 0][dx + 1];
          sum += w2 * p[dy + 0][dx + 2];
          sum += w3 * p[dy + 1][dx + 0];
          sum += w4 * p[dy + 1][dx + 1];
          sum += w5 * p[dy + 1][dx + 2];
          sum += w6 * p[dy + 2][dx + 0];
          sum += w7 * p[dy + 2][dx + 1];
          sum += w8 * p[dy + 2][dx + 2];
          acc[oci][dy * 2 + dx] = sum;
        }
    }
  }

  uint8_t* xqs = xq + (size_t)s * 8192;
#pragma unroll
  for (int oci = 0; oci < 16; ++oci) {
    int oc = wav * 16 + oci;
    float bv = bias[oc];
    int cnt = 0;
#pragma unroll
    for (int pix = 0; pix < 4; ++pix) {
      // acc holds sum(w*n); 0.25*acc has identical roundings to sum(w*(n/4))
      float v = 0.25f * acc[oci][pix] + bv;
      cnt += (v > 1.0f) ? 1 : 0;
    }
    xqs[oc * 128 + (half * 8 + pr) * 8 + pc] = (uint8_t)cnt;
  }
}

// ---------------------------------------------------------------- fc1 (K-split)
__global__ __launch_bounds__(256) void k_fc1(const uint8_t* __restrict__ xq,
                                             const float* __restrict__ w1,  // [256][8192]
                                             float* __restrict__ part) {
  __shared__ float wT[32 * 256];  // [k][o]
  __shared__ float xT[32 * 68];   // [k][s], stride 68
  const int t = threadIdx.x;
  const int sblk = blockIdx.x >> 5;   // 16 sample tiles of 64
  const int kblk = blockIdx.x & 31;   // 32 K tiles of 256
  const int sb = sblk * 64;
  const int o_base = (t & 63) * 4;
  const int s_base = (t >> 6) * 16;

  float acc[4][16];
#pragma unroll
  for (int oi = 0; oi < 4; ++oi)
#pragma unroll
    for (int si = 0; si < 16; ++si) acc[oi][si] = 0.0f;

  for (int kc = 0; kc < 8; ++kc) {
    const int k0 = kblk * 256 + kc * 32;
    __syncthreads();
    {  // stage weights, coalesced 128B row chunks
      int li = t & 7, ob = t >> 3;
#pragma unroll
      for (int i = 0; i < 8; ++i) {
        int o = ob + 32 * i;
        float4 v = *(const float4*)(w1 + (size_t)o * 8192 + k0 + li * 4);
        wT[(li * 4 + 0) * 256 + o] = v.x;
        wT[(li * 4 + 1) * 256 + o] = v.y;
        wT[(li * 4 + 2) * 256 + o] = v.z;
        wT[(li * 4 + 3) * 256 + o] = v.w;
      }
    }
    {  // stage activations (u8 counts -> f32)
#pragma unroll
      for (int rep = 0; rep < 2; ++rep) {
        int idx = t + rep * 256;        // 64 s x 8 quads
        int si = idx >> 3, q = idx & 7;
        uchar4 u = *(const uchar4*)(xq + (size_t)(sb + si) * 8192 + k0 + q * 4);
        xT[(q * 4 + 0) * 68 + si] = (float)u.x;
        xT[(q * 4 + 1) * 68 + si] = (float)u.y;
        xT[(q * 4 + 2) * 68 + si] = (float)u.z;
        xT[(q * 4 + 3) * 68 + si] = (float)u.w;
      }
    }
    __syncthreads();
#pragma unroll 2
    for (int k = 0; k < 32; ++k) {
      float4 wv = *(const float4*)&wT[k * 256 + o_base];
      float4 x0 = *(const float4*)&xT[k * 68 + s_base];
      float4 x1 = *(const float4*)&xT[k * 68 + s_base + 4];
      float4 x2 = *(const float4*)&xT[k * 68 + s_base + 8];
      float4 x3 = *(const float4*)&xT[k * 68 + s_base + 12];
      float xs[16] = {x0.x, x0.y, x0.z, x0.w, x1.x, x1.y, x1.z, x1.w,
                      x2.x, x2.y, x2.z, x2.w, x3.x, x3.y, x3.z, x3.w};
      float wa[4] = {wv.x, wv.y, wv.z, wv.w};
#pragma unroll
      for (int oi = 0; oi < 4; ++oi)
#pragma unroll
        for (int si = 0; si < 16; ++si) acc[oi][si] += wa[oi] * xs[si];
    }
  }

  float* pout = part + (size_t)kblk * (1024 * 256);
#pragma unroll
  for (int oi = 0; oi < 4; ++oi)
#pragma unroll
    for (int si = 0; si < 16; ++si)
      pout[(size_t)(sb + s_base + si) * 256 + o_base + oi] = 0.25f * acc[oi][si];
}

__global__ __launch_bounds__(256) void k_fc1_reduce(const float* __restrict__ part,
                                                    const float* __restrict__ b1,
                                                    float* __restrict__ cur3) {
  int idx = blockIdx.x * 256 + threadIdx.x;  // 1024 blocks x 256
  int o = idx & 255;
  float s = 0.0f;
  for (int kb = 0; kb < 32; ++kb) s += part[(size_t)kb * (1024 * 256) + idx];
  cur3[idx] = s + b1[o];   // bias added last, like the reference
}

// ---------------------------------------------------------------- LIF recurrence
__global__ __launch_bounds__(512) void k_lif(const float* __restrict__ cur3,
                                             const float* __restrict__ w2t,  // [256][128]
                                             const float* __restrict__ b2,
                                             const float* __restrict__ w3,   // [10][128]
                                             const float* __restrict__ b3,
                                             float* __restrict__ out) {
  __shared__ float spk3f[256][4];
  __shared__ float part[4][128][4];
  __shared__ float spk4f[128][4];
  __shared__ float w3l[10 * 132];
  const int t = threadIdx.x;
  const int sb = blockIdx.x * 4;    // 4 samples per block, grid 256 = 1/CU

  for (int idx = t; idx < 1280; idx += 512) {
    int cls = idx >> 7, k = idx & 127;
    w3l[cls * 132 + k] = w3[idx];
  }
  // phase-1 state
  const int i3 = t & 255;
  const int sp = t >> 8;
  float mem3a = 0.0f, mem3b = 0.0f;
  const float cur3a = cur3[(size_t)(sb + sp * 2 + 0) * 256 + i3];
  const float cur3b = cur3[(size_t)(sb + sp * 2 + 1) * 256 + i3];
  // phase-2: j neuron, h quarter of the i-range
  const int j2 = t & 127;
  const int h2 = t >> 7;
  // preload this thread's loop-invariant w2t column chunk into registers
  // (grid = 1 block/CU, only 8 waves -> VGPR headroom is huge)
  float wreg[64];
#pragma unroll
  for (int ii = 0; ii < 64; ++ii)
    wreg[ii] = w2t[(size_t)(h2 * 64 + ii) * 128 + j2];
  // phase-2b state (threads 0..127)
  float mem4[4] = {0.f, 0.f, 0.f, 0.f};
  const float b2v = (t < 128) ? b2[t] : 0.0f;
  // phase-3 state (threads 0..63 -> 4 samples x 16 slots, 10 active)
  const int s5 = t >> 4, cls5 = t & 15;
  float mem5 = 0.0f;
  const float b3v = (t < 64 && cls5 < 10) ? b3[cls5] : 0.0f;
  __syncthreads();

  for (int step = 0; step < NSTEP; ++step) {
    // ---- layer 3
    mem3a = lif_update(mem3a, cur3a);
    mem3b = lif_update(mem3b, cur3b);
    spk3f[i3][sp * 2 + 0] = (mem3a > 1.0f) ? 1.0f : 0.0f;
    spk3f[i3][sp * 2 + 1] = (mem3b > 1.0f) ? 1.0f : 0.0f;
    __syncthreads();
    // ---- layer 4 partial dot (weights in registers, spikes via LDS broadcast)
    {
      float a0 = 0.f, a1 = 0.f, a2 = 0.f, a3 = 0.f;
      const float4* sp4 = (const float4*)&spk3f[h2 * 64][0];
#pragma unroll
      for (int ii = 0; ii < 64; ++ii) {
        float4 sv = sp4[ii];           // wave-uniform -> LDS broadcast
        float wv = wreg[ii];
        a0 += wv * sv.x; a1 += wv * sv.y; a2 += wv * sv.z; a3 += wv * sv.w;
      }
      float4 pv = {a0, a1, a2, a3};
      *(float4*)&part[h2][j2][0] = pv;
    }
    __syncthreads();
    // ---- layer 4 combine + LIF
    if (t < 128) {
#pragma unroll
      for (int s = 0; s < 4; ++s) {
        float sum = (part[0][t][s] + part[1][t][s]) + (part[2][t][s] + part[3][t][s]);
        float cur4 = sum + b2v;
        mem4[s] = lif_update(mem4[s], cur4);
        spk4f[t][s] = (mem4[s] > 1.0f) ? 1.0f : 0.0f;
      }
    }
    __syncthreads();
    // ---- layer 5
    if (t < 64 && cls5 < 10) {
      float a5 = 0.0f;
#pragma unroll 8
      for (int k = 0; k < 128; ++k)
        a5 += spk4f[k][s5] * w3l[cls5 * 132 + k];
      float cur5 = a5 + b3v;
      mem5 = lif_update(mem5, cur5);
      out[(size_t)step * 10240 + (size_t)(sb + s5) * 10 + cls5] =
          (mem5 > 1.0f) ? 1.0f : 0.0f;
    }
    __syncthreads();
  }
}

// ---------------------------------------------------------------- launcher
extern "C" void kernel_launch(void* const* d_in, const int* in_sizes, int n_in,
                              void* d_out, int out_size, void* d_ws, size_t ws_size,
                              hipStream_t stream) {
  (void)in_sizes; (void)n_in; (void)out_size; (void)ws_size;
  const float* x   = (const float*)d_in[0];
  const float* w1c = (const float*)d_in[1];
  const float* b1c = (const float*)d_in[2];
  const float* w2c = (const float*)d_in[3];
  const float* b2c = (const float*)d_in[4];
  const float* fw1 = (const float*)d_in[5];
  const float* fb1 = (const float*)d_in[6];
  const float* fw2 = (const float*)d_in[7];
  const float* fb2 = (const float*)d_in[8];
  const float* fw3 = (const float*)d_in[9];
  const float* fb3 = (const float*)d_in[10];
  float* out = (float*)d_out;

  char* ws = (char*)d_ws;
  uint8_t* c1   = (uint8_t*)ws;                       // 16 MB
  uint8_t* xq   = (uint8_t*)(ws + (16u << 20));       //  8 MB
  float*   cur3 = (float*)(ws + (24u << 20));         //  1 MB
  float*   w2t  = (float*)(ws + (25u << 20));         // 128 KB
  float*   part = (float*)(ws + (26u << 20));         // 32 MB

  k_w2t<<<dim3(128), dim3(256), 0, stream>>>(fw2, w2t);
  k_conv1<<<dim3(1024), dim3(256), 0, stream>>>(x, w1c, b1c, c1);
  k_conv2<<<dim3(2048), dim3(256), 0, stream>>>(c1, w2c, b2c, xq);
  k_fc1<<<dim3(512), dim3(256), 0, stream>>>(xq, fw1, part);
  k_fc1_reduce<<<dim3(1024), dim3(256), 0, stream>>>(part, fb1, cur3);
  k_lif<<<dim3(256), dim3(512), 0, stream>>>(cur3, w2t, fb2, fw3, fb3, out);
}

// Round 3
// 284.498 us; speedup vs baseline: 1.4981x; 1.4981x over previous
//
#include <hip/hip_runtime.h>
#include <stdint.h>

// AudioSNN: conv1(1->32)+spike+pool -> conv2(32->64)+spike+pool -> fc1
// -> 25-step LIF (fc2, fc3).
// conv2 now runs on MFMA: activations are exact integers 0..4 (exact fp16),
// weights use an exact 2-way fp16 split (err ~2^-22) -> fp32-faithful spikes.
//
// ws layout (region A aliased: c1 used by conv1/conv2, part by fc1 after):
//   A    : c1 fp16 [1024][32y][16x][32ch]  32 MB  /  part f32 [32][1024][256] 32 MB
//   xq   u8  [1024][8192]          @32M   8 MB
//   cur3 f32 [1024][256]           @40M   1 MB
//   w2t  f32 [256][128]            @41M   128 KB
//   afrag f16 [9][4][2][512]       @41M+128K  72 KB  (conv2 A fragments hi/lo)

#define NSTEP 25

using half8  = __attribute__((ext_vector_type(8))) _Float16;
using float4v = __attribute__((ext_vector_type(4))) float;

__device__ __forceinline__ float lif_update(float mem, float cur) {
#pragma clang fp contract(off)
  float reset = (mem > 1.0f) ? 1.0f : 0.0f;
  float m = 0.95f * mem;
  m = m + cur;
  m = m - reset;
  return m;
}

// ---------------------------------------------------------------- w2 transpose
__global__ __launch_bounds__(256) void k_w2t(const float* __restrict__ w2,
                                             float* __restrict__ w2t) {
  const int j = blockIdx.x;    // 128
  const int i = threadIdx.x;   // 256
  w2t[i * 128 + j] = w2[j * 256 + i];
}

// ------------------------------------------------- conv2 A-fragment prep (split)
// afrag[((tap*4+mt)*2+sp)*512 + lane*8 + j] ; A[m=lane&15][k=quad*8+j], k=ch.
__global__ __launch_bounds__(64) void k_prep(const float* __restrict__ w2c,
                                             _Float16* __restrict__ afrag) {
  const int b = blockIdx.x;         // 72 = 9 taps x 4 mtiles x 2 splits
  const int tp = b >> 3;
  const int mt = (b & 7) >> 1;
  const int sp = b & 1;
  const int lane = threadIdx.x;
  const int m = lane & 15, quad = lane >> 4;
#pragma unroll
  for (int j = 0; j < 8; ++j) {
    int ch = quad * 8 + j;
    int oc = mt * 16 + m;
    float wv = w2c[(size_t)(oc * 32 + ch) * 9 + tp];
    float hi = (float)(_Float16)wv;
    _Float16 val = (sp == 0) ? (_Float16)wv : (_Float16)(wv - hi);
    afrag[(size_t)b * 512 + lane * 8 + j] = val;
  }
}

// ---------------------------------------------------------------- conv1 fused
// Output: fp16 pool-counts, layout [s][pos(512)][ch(32)] (channel-innermost).
__global__ __launch_bounds__(256) void k_conv1(const float* __restrict__ x,
                                               const float* __restrict__ w,
                                               const float* __restrict__ bias,
                                               _Float16* __restrict__ c1) {
  __shared__ float xin[66 * 34];   // 64x32 + SAME halo, zero padded
  __shared__ float wl[288];
  __shared__ float bl[32];
  const int t = threadIdx.x;
  const int s = blockIdx.x;

  for (int idx = t; idx < 66 * 34; idx += 256) xin[idx] = 0.0f;
  wl[t] = w[t];
  if (t < 32) { wl[256 + t] = w[256 + t]; bl[t] = bias[t]; }
  __syncthreads();

  const float* xs = x + (size_t)s * (64 * 32);
#pragma unroll
  for (int r = 0; r < 2; ++r) {
    int idx = t + r * 256;
    int y = idx >> 3, q = idx & 7;
    float4 v = *(const float4*)(xs + y * 32 + q * 4);
    float* dst = &xin[(y + 1) * 34 + q * 4 + 1];
    dst[0] = v.x; dst[1] = v.y; dst[2] = v.z; dst[3] = v.w;
  }
  __syncthreads();

  const int ch = t & 31;          // lane-major channel -> coalesced fp16 writes
  const int po = t >> 5;          // 8 positions per iter
  float wc[9];
#pragma unroll
  for (int i = 0; i < 9; ++i) wc[i] = wl[ch * 9 + i];
  const float bv = bl[ch];

  _Float16* c1s = c1 + (size_t)s * (512 * 32);
  for (int rr = 0; rr < 64; ++rr) {
    int pos = rr * 8 + po;
    int py = pos >> 4, px = pos & 15;
    float p[4][4];
#pragma unroll
    for (int rw = 0; rw < 4; ++rw) {
      float2 a = *(const float2*)&xin[(2 * py + rw) * 34 + 2 * px];
      float2 b = *(const float2*)&xin[(2 * py + rw) * 34 + 2 * px + 2];
      p[rw][0] = a.x; p[rw][1] = a.y; p[rw][2] = b.x; p[rw][3] = b.y;
    }
    int cnt = 0;
#pragma unroll
    for (int dy = 0; dy < 2; ++dy)
#pragma unroll
      for (int dx = 0; dx < 2; ++dx) {
        float acc = 0.0f;
#pragma unroll
        for (int ky = 0; ky < 3; ++ky)
#pragma unroll
          for (int kx = 0; kx < 3; ++kx)
            acc += wc[ky * 3 + kx] * p[dy + ky][dx + kx];
        float v = acc + bv;
        cnt += (v > 1.0f) ? 1 : 0;
      }
    c1s[pos * 32 + ch] = (_Float16)(float)cnt;
  }
}

// ---------------------------------------------------------------- conv2 (MFMA)
// Block = one sample. Implicit GEMM: M=64 oc, N=512 pos, K=32 ch per tap x 9.
// B-frag: cin[y+ky][x+kx][quad*8..+7] as one ds_read_b128 (ch-innermost LDS).
__global__ __launch_bounds__(256, 2) void k_conv2(const _Float16* __restrict__ c1,
                                                  const _Float16* __restrict__ afrag,
                                                  const float* __restrict__ bias,
                                                  uint8_t* __restrict__ xq) {
  __shared__ _Float16 cin[34 * 18 * 40];   // [row 34][col 18][ch pad 40] 48960 B
  const int t = threadIdx.x;
  const int s = blockIdx.x;

  {  // zero init (covers halo pads)
    half8* cp = (half8*)cin;
    half8 z = {};
    for (int idx = t; idx < 3060; idx += 256) cp[idx] = z;
  }
  __syncthreads();

  const _Float16* c1s = c1 + (size_t)s * (512 * 32);
#pragma unroll
  for (int i = 0; i < 8; ++i) {   // 2048 groups = 32y x 16x x 4 ch-octets
    int g = t + i * 256;
    int y = g >> 6, r = g & 63, x = r >> 2, oct = r & 3;
    half8 v = *(const half8*)(c1s + (y * 16 + x) * 32 + oct * 8);
    *(half8*)&cin[((y + 1) * 18 + (x + 1)) * 40 + oct * 8] = v;
  }
  __syncthreads();

  const int lane = t & 63;
  const int wave = __builtin_amdgcn_readfirstlane(t >> 6);
  const int xlane = lane & 15, quad = lane >> 4;

  float4v acc[4][8];
#pragma unroll
  for (int mt = 0; mt < 4; ++mt)
#pragma unroll
    for (int nt = 0; nt < 8; ++nt) acc[mt][nt] = (float4v){0.f, 0.f, 0.f, 0.f};

  for (int ky = 0; ky < 3; ++ky)
    for (int kx = 0; kx < 3; ++kx) {
      const int tp = ky * 3 + kx;
      half8 a[4][2];
#pragma unroll
      for (int mt = 0; mt < 4; ++mt)
#pragma unroll
        for (int sp = 0; sp < 2; ++sp)
          a[mt][sp] = *(const half8*)(afrag +
                        ((size_t)((tp * 4 + mt) * 2 + sp)) * 512 + lane * 8);
#pragma unroll
      for (int nt = 0; nt < 8; ++nt) {
        int row = wave * 8 + nt + ky;     // y + ky (pad row 0 = y=-1)
        int col = xlane + kx;             // x + kx
        half8 b = *(const half8*)&cin[(row * 18 + col) * 40 + quad * 8];
#pragma unroll
        for (int mt = 0; mt < 4; ++mt) {
          acc[mt][nt] = __builtin_amdgcn_mfma_f32_16x16x32_f16(a[mt][0], b,
                                                               acc[mt][nt], 0, 0, 0);
          acc[mt][nt] = __builtin_amdgcn_mfma_f32_16x16x32_f16(a[mt][1], b,
                                                               acc[mt][nt], 0, 0, 0);
        }
      }
    }

  // Epilogue: v = 0.25*acc + bias; spike; 2x2 pool (y-pairs in-lane, x via shfl).
  float bw[4][4];
#pragma unroll
  for (int mt = 0; mt < 4; ++mt)
#pragma unroll
    for (int r = 0; r < 4; ++r) bw[mt][r] = bias[mt * 16 + quad * 4 + r];

  uint8_t* xqs = xq + (size_t)s * 8192;
  const int px = xlane >> 1;
  const bool writer = (xlane & 1) == 0;
#pragma unroll
  for (int mt = 0; mt < 4; ++mt)
#pragma unroll
    for (int ntp = 0; ntp < 4; ++ntp) {
      int py = wave * 4 + ntp;
#pragma unroll
      for (int r = 0; r < 4; ++r) {
        float v0 = 0.25f * acc[mt][2 * ntp + 0][r] + bw[mt][r];
        float v1 = 0.25f * acc[mt][2 * ntp + 1][r] + bw[mt][r];
        int c = ((v0 > 1.0f) ? 1 : 0) + ((v1 > 1.0f) ? 1 : 0);
        c += __shfl_xor(c, 1, 64);
        if (writer) {
          int oc = mt * 16 + quad * 4 + r;
          xqs[oc * 128 + py * 8 + px] = (uint8_t)c;
        }
      }
    }
}

// ---------------------------------------------------------------- fc1 (K-split)
__global__ __launch_bounds__(256) void k_fc1(const uint8_t* __restrict__ xq,
                                             const float* __restrict__ w1,  // [256][8192]
                                             float* __restrict__ part) {
  __shared__ float wT[32 * 256];  // [k][o]
  __shared__ float xT[32 * 68];   // [k][s]
  const int t = threadIdx.x;
  const int sblk = blockIdx.x >> 5;
  const int kblk = blockIdx.x & 31;
  const int sb = sblk * 64;
  const int o_base = (t & 63) * 4;
  const int s_base = (t >> 6) * 16;

  float acc[4][16];
#pragma unroll
  for (int oi = 0; oi < 4; ++oi)
#pragma unroll
    for (int si = 0; si < 16; ++si) acc[oi][si] = 0.0f;

  for (int kc = 0; kc < 8; ++kc) {
    const int k0 = kblk * 256 + kc * 32;
    __syncthreads();
    {
      int li = t & 7, ob = t >> 3;
#pragma unroll
      for (int i = 0; i < 8; ++i) {
        int o = ob + 32 * i;
        float4 v = *(const float4*)(w1 + (size_t)o * 8192 + k0 + li * 4);
        wT[(li * 4 + 0) * 256 + o] = v.x;
        wT[(li * 4 + 1) * 256 + o] = v.y;
        wT[(li * 4 + 2) * 256 + o] = v.z;
        wT[(li * 4 + 3) * 256 + o] = v.w;
      }
    }
    {
#pragma unroll
      for (int rep = 0; rep < 2; ++rep) {
        int idx = t + rep * 256;
        int si = idx >> 3, q = idx & 7;
        uchar4 u = *(const uchar4*)(xq + (size_t)(sb + si) * 8192 + k0 + q * 4);
        xT[(q * 4 + 0) * 68 + si] = (float)u.x;
        xT[(q * 4 + 1) * 68 + si] = (float)u.y;
        xT[(q * 4 + 2) * 68 + si] = (float)u.z;
        xT[(q * 4 + 3) * 68 + si] = (float)u.w;
      }
    }
    __syncthreads();
#pragma unroll 2
    for (int k = 0; k < 32; ++k) {
      float4 wv = *(const float4*)&wT[k * 256 + o_base];
      float4 x0 = *(const float4*)&xT[k * 68 + s_base];
      float4 x1 = *(const float4*)&xT[k * 68 + s_base + 4];
      float4 x2 = *(const float4*)&xT[k * 68 + s_base + 8];
      float4 x3 = *(const float4*)&xT[k * 68 + s_base + 12];
      float xs[16] = {x0.x, x0.y, x0.z, x0.w, x1.x, x1.y, x1.z, x1.w,
                      x2.x, x2.y, x2.z, x2.w, x3.x, x3.y, x3.z, x3.w};
      float wa[4] = {wv.x, wv.y, wv.z, wv.w};
#pragma unroll
      for (int oi = 0; oi < 4; ++oi)
#pragma unroll
        for (int si = 0; si < 16; ++si) acc[oi][si] += wa[oi] * xs[si];
    }
  }

  float* pout = part + (size_t)kblk * (1024 * 256);
#pragma unroll
  for (int oi = 0; oi < 4; ++oi)
#pragma unroll
    for (int si = 0; si < 16; ++si)
      pout[(size_t)(sb + s_base + si) * 256 + o_base + oi] = 0.25f * acc[oi][si];
}

__global__ __launch_bounds__(256) void k_fc1_reduce(const float* __restrict__ part,
                                                    const float* __restrict__ b1,
                                                    float* __restrict__ cur3) {
  int idx = blockIdx.x * 256 + threadIdx.x;
  int o = idx & 255;
  float s = 0.0f;
  for (int kb = 0; kb < 32; ++kb) s += part[(size_t)kb * (1024 * 256) + idx];
  cur3[idx] = s + b1[o];
}

// ---------------------------------------------------------------- LIF recurrence
__global__ __launch_bounds__(512) void k_lif(const float* __restrict__ cur3,
                                             const float* __restrict__ w2t,  // [256][128]
                                             const float* __restrict__ b2,
                                             const float* __restrict__ w3,   // [10][128]
                                             const float* __restrict__ b3,
                                             float* __restrict__ out) {
  __shared__ float spk3f[256][4];
  __shared__ float part[4][128][4];
  __shared__ float spk4f[128][4];
  __shared__ float w3l[10 * 132];
  const int t = threadIdx.x;
  const int sb = blockIdx.x * 4;

  for (int idx = t; idx < 1280; idx += 512) {
    int cls = idx >> 7, k = idx & 127;
    w3l[cls * 132 + k] = w3[idx];
  }
  const int i3 = t & 255;
  const int sp = t >> 8;
  float mem3a = 0.0f, mem3b = 0.0f;
  const float cur3a = cur3[(size_t)(sb + sp * 2 + 0) * 256 + i3];
  const float cur3b = cur3[(size_t)(sb + sp * 2 + 1) * 256 + i3];
  const int j2 = t & 127;
  const int h2 = t >> 7;
  float wreg[64];
#pragma unroll
  for (int ii = 0; ii < 64; ++ii)
    wreg[ii] = w2t[(size_t)(h2 * 64 + ii) * 128 + j2];
  float mem4[4] = {0.f, 0.f, 0.f, 0.f};
  const float b2v = (t < 128) ? b2[t] : 0.0f;
  const int s5 = t >> 4, cls5 = t & 15;
  float mem5 = 0.0f;
  const float b3v = (t < 64 && cls5 < 10) ? b3[cls5] : 0.0f;
  __syncthreads();

  for (int step = 0; step < NSTEP; ++step) {
    mem3a = lif_update(mem3a, cur3a);
    mem3b = lif_update(mem3b, cur3b);
    spk3f[i3][sp * 2 + 0] = (mem3a > 1.0f) ? 1.0f : 0.0f;
    spk3f[i3][sp * 2 + 1] = (mem3b > 1.0f) ? 1.0f : 0.0f;
    __syncthreads();
    {
      float a0 = 0.f, a1 = 0.f, a2 = 0.f, a3 = 0.f;
      const float4* sp4 = (const float4*)&spk3f[h2 * 64][0];
#pragma unroll
      for (int ii = 0; ii < 64; ++ii) {
        float4 sv = sp4[ii];
        float wv = wreg[ii];
        a0 += wv * sv.x; a1 += wv * sv.y; a2 += wv * sv.z; a3 += wv * sv.w;
      }
      float4 pv = {a0, a1, a2, a3};
      *(float4*)&part[h2][j2][0] = pv;
    }
    __syncthreads();
    if (t < 128) {
#pragma unroll
      for (int s = 0; s < 4; ++s) {
        float sum = (part[0][t][s] + part[1][t][s]) + (part[2][t][s] + part[3][t][s]);
        float cur4 = sum + b2v;
        mem4[s] = lif_update(mem4[s], cur4);
        spk4f[t][s] = (mem4[s] > 1.0f) ? 1.0f : 0.0f;
      }
    }
    __syncthreads();
    if (t < 64 && cls5 < 10) {
      float a5 = 0.0f;
#pragma unroll 8
      for (int k = 0; k < 128; ++k)
        a5 += spk4f[k][s5] * w3l[cls5 * 132 + k];
      float cur5 = a5 + b3v;
      mem5 = lif_update(mem5, cur5);
      out[(size_t)step * 10240 + (size_t)(sb + s5) * 10 + cls5] =
          (mem5 > 1.0f) ? 1.0f : 0.0f;
    }
    __syncthreads();
  }
}

// ---------------------------------------------------------------- launcher
extern "C" void kernel_launch(void* const* d_in, const int* in_sizes, int n_in,
                              void* d_out, int out_size, void* d_ws, size_t ws_size,
                              hipStream_t stream) {
  (void)in_sizes; (void)n_in; (void)out_size; (void)ws_size;
  const float* x   = (const float*)d_in[0];
  const float* w1c = (const float*)d_in[1];
  const float* b1c = (const float*)d_in[2];
  const float* w2c = (const float*)d_in[3];
  const float* b2c = (const float*)d_in[4];
  const float* fw1 = (const float*)d_in[5];
  const float* fb1 = (const float*)d_in[6];
  const float* fw2 = (const float*)d_in[7];
  const float* fb2 = (const float*)d_in[8];
  const float* fw3 = (const float*)d_in[9];
  const float* fb3 = (const float*)d_in[10];
  float* out = (float*)d_out;

  char* ws = (char*)d_ws;
  _Float16* c1    = (_Float16*)ws;                    // 32 MB (conv phase)
  float*    part  = (float*)ws;                       // 32 MB (fc1 phase, aliased)
  uint8_t*  xq    = (uint8_t*)(ws + (32u << 20));     //  8 MB
  float*    cur3  = (float*)(ws + (40u << 20));       //  1 MB
  float*    w2t   = (float*)(ws + (41u << 20));       // 128 KB
  _Float16* afrag = (_Float16*)(ws + (41u << 20) + (128u << 10));  // 72 KB

  k_w2t<<<dim3(128), dim3(256), 0, stream>>>(fw2, w2t);
  k_prep<<<dim3(72), dim3(64), 0, stream>>>(w2c, afrag);
  k_conv1<<<dim3(1024), dim3(256), 0, stream>>>(x, w1c, b1c, c1);
  k_conv2<<<dim3(1024), dim3(256), 0, stream>>>(c1, afrag, b2c, xq);
  k_fc1<<<dim3(512), dim3(256), 0, stream>>>(xq, fw1, part);
  k_fc1_reduce<<<dim3(1024), dim3(256), 0, stream>>>(part, fb1, cur3);
  k_lif<<<dim3(256), dim3(512), 0, stream>>>(cur3, w2t, fb2, fw3, fb3, out);
}

// Round 4
// 243.559 us; speedup vs baseline: 1.7499x; 1.1681x over previous
//
#include <hip/hip_runtime.h>
#include <stdint.h>

// AudioSNN: conv1(1->32)+spike+pool -> conv2(32->64)+spike+pool -> fc1
// -> 25-step LIF (fc2, fc3).
// conv2 AND the recurrent fc2/fc3 run on MFMA: activations/spikes are exact
// small integers (exact fp16), weights use an exact 2-way fp16 split
// (err ~2^-22) -> fp32-faithful spike decisions (absmax 0 in R3).
//
// ws layout (region A aliased: c1 used by conv1/conv2, part by fc1 after):
//   A    : c1 fp16 [1024][32y][16x][32ch]  32 MB  /  part f32 [32][1024][256] 32 MB
//   xq   u8  [1024][8192]          @32M   8 MB
//   cur3 f32 [1024][256]           @40M   1 MB
//   afrag f16 [9][4][2][512]       @41M   72 KB  (conv2 A fragments hi/lo)

#define NSTEP 25

using half8   = __attribute__((ext_vector_type(8))) _Float16;
using half4v  = __attribute__((ext_vector_type(4))) _Float16;
using float4v = __attribute__((ext_vector_type(4))) float;

__device__ __forceinline__ float lif_update(float mem, float cur) {
#pragma clang fp contract(off)
  float reset = (mem > 1.0f) ? 1.0f : 0.0f;
  float m = 0.95f * mem;
  m = m + cur;
  m = m - reset;
  return m;
}

// ------------------------------------------------- conv2 A-fragment prep (split)
__global__ __launch_bounds__(64) void k_prep(const float* __restrict__ w2c,
                                             _Float16* __restrict__ afrag) {
  const int b = blockIdx.x;         // 72 = 9 taps x 4 mtiles x 2 splits
  const int tp = b >> 3;
  const int mt = (b & 7) >> 1;
  const int sp = b & 1;
  const int lane = threadIdx.x;
  const int m = lane & 15, quad = lane >> 4;
#pragma unroll
  for (int j = 0; j < 8; ++j) {
    int ch = quad * 8 + j;
    int oc = mt * 16 + m;
    float wv = w2c[(size_t)(oc * 32 + ch) * 9 + tp];
    float hi = (float)(_Float16)wv;
    _Float16 val = (sp == 0) ? (_Float16)wv : (_Float16)(wv - hi);
    afrag[(size_t)b * 512 + lane * 8 + j] = val;
  }
}

// ---------------------------------------------------------------- conv1 fused
// Output: fp16 pool-counts, layout [s][pos(512)][ch(32)] (channel-innermost).
__global__ __launch_bounds__(256) void k_conv1(const float* __restrict__ x,
                                               const float* __restrict__ w,
                                               const float* __restrict__ bias,
                                               _Float16* __restrict__ c1) {
  __shared__ float xin[66 * 34];   // 64x32 + SAME halo, zero padded
  __shared__ float wl[288];
  __shared__ float bl[32];
  const int t = threadIdx.x;
  const int s = blockIdx.x;

  for (int idx = t; idx < 66 * 34; idx += 256) xin[idx] = 0.0f;
  wl[t] = w[t];
  if (t < 32) { wl[256 + t] = w[256 + t]; bl[t] = bias[t]; }
  __syncthreads();

  const float* xs = x + (size_t)s * (64 * 32);
#pragma unroll
  for (int r = 0; r < 2; ++r) {
    int idx = t + r * 256;
    int y = idx >> 3, q = idx & 7;
    float4 v = *(const float4*)(xs + y * 32 + q * 4);
    float* dst = &xin[(y + 1) * 34 + q * 4 + 1];
    dst[0] = v.x; dst[1] = v.y; dst[2] = v.z; dst[3] = v.w;
  }
  __syncthreads();

  const int ch = t & 31;
  const int po = t >> 5;
  float wc[9];
#pragma unroll
  for (int i = 0; i < 9; ++i) wc[i] = wl[ch * 9 + i];
  const float bv = bl[ch];

  _Float16* c1s = c1 + (size_t)s * (512 * 32);
  for (int rr = 0; rr < 64; ++rr) {
    int pos = rr * 8 + po;
    int py = pos >> 4, px = pos & 15;
    float p[4][4];
#pragma unroll
    for (int rw = 0; rw < 4; ++rw) {
      float2 a = *(const float2*)&xin[(2 * py + rw) * 34 + 2 * px];
      float2 b = *(const float2*)&xin[(2 * py + rw) * 34 + 2 * px + 2];
      p[rw][0] = a.x; p[rw][1] = a.y; p[rw][2] = b.x; p[rw][3] = b.y;
    }
    int cnt = 0;
#pragma unroll
    for (int dy = 0; dy < 2; ++dy)
#pragma unroll
      for (int dx = 0; dx < 2; ++dx) {
        float acc = 0.0f;
#pragma unroll
        for (int ky = 0; ky < 3; ++ky)
#pragma unroll
          for (int kx = 0; kx < 3; ++kx)
            acc += wc[ky * 3 + kx] * p[dy + ky][dx + kx];
        float v = acc + bv;
        cnt += (v > 1.0f) ? 1 : 0;
      }
    c1s[pos * 32 + ch] = (_Float16)(float)cnt;
  }
}

// ---------------------------------------------------------------- conv2 (MFMA)
__global__ __launch_bounds__(256, 2) void k_conv2(const _Float16* __restrict__ c1,
                                                  const _Float16* __restrict__ afrag,
                                                  const float* __restrict__ bias,
                                                  uint8_t* __restrict__ xq) {
  __shared__ _Float16 cin[34 * 18 * 40];   // [row 34][col 18][ch pad 40]
  const int t = threadIdx.x;
  const int s = blockIdx.x;

  {
    half8* cp = (half8*)cin;
    half8 z = {};
    for (int idx = t; idx < 3060; idx += 256) cp[idx] = z;
  }
  __syncthreads();

  const _Float16* c1s = c1 + (size_t)s * (512 * 32);
#pragma unroll
  for (int i = 0; i < 8; ++i) {
    int g = t + i * 256;
    int y = g >> 6, r = g & 63, x = r >> 2, oct = r & 3;
    half8 v = *(const half8*)(c1s + (y * 16 + x) * 32 + oct * 8);
    *(half8*)&cin[((y + 1) * 18 + (x + 1)) * 40 + oct * 8] = v;
  }
  __syncthreads();

  const int lane = t & 63;
  const int wave = __builtin_amdgcn_readfirstlane(t >> 6);
  const int xlane = lane & 15, quad = lane >> 4;

  float4v acc[4][8];
#pragma unroll
  for (int mt = 0; mt < 4; ++mt)
#pragma unroll
    for (int nt = 0; nt < 8; ++nt) acc[mt][nt] = (float4v){0.f, 0.f, 0.f, 0.f};

  for (int ky = 0; ky < 3; ++ky)
    for (int kx = 0; kx < 3; ++kx) {
      const int tp = ky * 3 + kx;
      half8 a[4][2];
#pragma unroll
      for (int mt = 0; mt < 4; ++mt)
#pragma unroll
        for (int sp = 0; sp < 2; ++sp)
          a[mt][sp] = *(const half8*)(afrag +
                        ((size_t)((tp * 4 + mt) * 2 + sp)) * 512 + lane * 8);
#pragma unroll
      for (int nt = 0; nt < 8; ++nt) {
        int row = wave * 8 + nt + ky;
        int col = xlane + kx;
        half8 b = *(const half8*)&cin[(row * 18 + col) * 40 + quad * 8];
#pragma unroll
        for (int mt = 0; mt < 4; ++mt) {
          acc[mt][nt] = __builtin_amdgcn_mfma_f32_16x16x32_f16(a[mt][0], b,
                                                               acc[mt][nt], 0, 0, 0);
          acc[mt][nt] = __builtin_amdgcn_mfma_f32_16x16x32_f16(a[mt][1], b,
                                                               acc[mt][nt], 0, 0, 0);
        }
      }
    }

  float bw[4][4];
#pragma unroll
  for (int mt = 0; mt < 4; ++mt)
#pragma unroll
    for (int r = 0; r < 4; ++r) bw[mt][r] = bias[mt * 16 + quad * 4 + r];

  uint8_t* xqs = xq + (size_t)s * 8192;
  const int px = xlane >> 1;
  const bool writer = (xlane & 1) == 0;
#pragma unroll
  for (int mt = 0; mt < 4; ++mt)
#pragma unroll
    for (int ntp = 0; ntp < 4; ++ntp) {
      int py = wave * 4 + ntp;
#pragma unroll
      for (int r = 0; r < 4; ++r) {
        float v0 = 0.25f * acc[mt][2 * ntp + 0][r] + bw[mt][r];
        float v1 = 0.25f * acc[mt][2 * ntp + 1][r] + bw[mt][r];
        int c = ((v0 > 1.0f) ? 1 : 0) + ((v1 > 1.0f) ? 1 : 0);
        c += __shfl_xor(c, 1, 64);
        if (writer) {
          int oc = mt * 16 + quad * 4 + r;
          xqs[oc * 128 + py * 8 + px] = (uint8_t)c;
        }
      }
    }
}

// ---------------------------------------------------------------- fc1 (K-split)
__global__ __launch_bounds__(256) void k_fc1(const uint8_t* __restrict__ xq,
                                             const float* __restrict__ w1,  // [256][8192]
                                             float* __restrict__ part) {
  __shared__ float wT[32 * 256];
  __shared__ float xT[32 * 68];
  const int t = threadIdx.x;
  const int sblk = blockIdx.x >> 5;
  const int kblk = blockIdx.x & 31;
  const int sb = sblk * 64;
  const int o_base = (t & 63) * 4;
  const int s_base = (t >> 6) * 16;

  float acc[4][16];
#pragma unroll
  for (int oi = 0; oi < 4; ++oi)
#pragma unroll
    for (int si = 0; si < 16; ++si) acc[oi][si] = 0.0f;

  for (int kc = 0; kc < 8; ++kc) {
    const int k0 = kblk * 256 + kc * 32;
    __syncthreads();
    {
      int li = t & 7, ob = t >> 3;
#pragma unroll
      for (int i = 0; i < 8; ++i) {
        int o = ob + 32 * i;
        float4 v = *(const float4*)(w1 + (size_t)o * 8192 + k0 + li * 4);
        wT[(li * 4 + 0) * 256 + o] = v.x;
        wT[(li * 4 + 1) * 256 + o] = v.y;
        wT[(li * 4 + 2) * 256 + o] = v.z;
        wT[(li * 4 + 3) * 256 + o] = v.w;
      }
    }
    {
#pragma unroll
      for (int rep = 0; rep < 2; ++rep) {
        int idx = t + rep * 256;
        int si = idx >> 3, q = idx & 7;
        uchar4 u = *(const uchar4*)(xq + (size_t)(sb + si) * 8192 + k0 + q * 4);
        xT[(q * 4 + 0) * 68 + si] = (float)u.x;
        xT[(q * 4 + 1) * 68 + si] = (float)u.y;
        xT[(q * 4 + 2) * 68 + si] = (float)u.z;
        xT[(q * 4 + 3) * 68 + si] = (float)u.w;
      }
    }
    __syncthreads();
#pragma unroll 2
    for (int k = 0; k < 32; ++k) {
      float4 wv = *(const float4*)&wT[k * 256 + o_base];
      float4 x0 = *(const float4*)&xT[k * 68 + s_base];
      float4 x1 = *(const float4*)&xT[k * 68 + s_base + 4];
      float4 x2 = *(const float4*)&xT[k * 68 + s_base + 8];
      float4 x3 = *(const float4*)&xT[k * 68 + s_base + 12];
      float xs[16] = {x0.x, x0.y, x0.z, x0.w, x1.x, x1.y, x1.z, x1.w,
                      x2.x, x2.y, x2.z, x2.w, x3.x, x3.y, x3.z, x3.w};
      float wa[4] = {wv.x, wv.y, wv.z, wv.w};
#pragma unroll
      for (int oi = 0; oi < 4; ++oi)
#pragma unroll
        for (int si = 0; si < 16; ++si) acc[oi][si] += wa[oi] * xs[si];
    }
  }

  float* pout = part + (size_t)kblk * (1024 * 256);
#pragma unroll
  for (int oi = 0; oi < 4; ++oi)
#pragma unroll
    for (int si = 0; si < 16; ++si)
      pout[(size_t)(sb + s_base + si) * 256 + o_base + oi] = 0.25f * acc[oi][si];
}

__global__ __launch_bounds__(256) void k_fc1_reduce(const float* __restrict__ part,
                                                    const float* __restrict__ b1,
                                                    float* __restrict__ cur3) {
  int idx = blockIdx.x * 256 + threadIdx.x;
  int o = idx & 255;
  float s = 0.0f;
  for (int kb = 0; kb < 32; ++kb) s += part[(size_t)kb * (1024 * 256) + idx];
  cur3[idx] = s + b1[o];
}

// ---------------------------------------------------------------- LIF recurrence
// MFMA recurrence: per step D2[16 j x 16 s] tiles (A = fc2 weight frags in
// VGPRs, exact fp16 split; B = spikes in LDS, layout [i-oct][sample][8]).
// LDS traffic/step: ~80 wave-instr vs ~640 before (broadcast-read bound).
__global__ __launch_bounds__(512, 2) void k_lif(const float* __restrict__ cur3,
                                                const float* __restrict__ w2,   // [128][256]
                                                const float* __restrict__ b2,
                                                const float* __restrict__ w3,   // [10][128]
                                                const float* __restrict__ b3,
                                                float* __restrict__ out) {
  __shared__ _Float16 spk3[1152];   // [oct32][s4][8] + pad (garbage cols n>=4)
  __shared__ _Float16 spk4[640];    // [oct16][s4][8] + pad
  const int t = threadIdx.x;
  const int sb = blockIdx.x * 4;    // 4 samples/block, grid 256 = 1 block/CU
  const int lane = t & 63;
  const int wave = __builtin_amdgcn_readfirstlane(t >> 6);  // = fc2 n-tile (j/16)
  const int n16 = lane & 15;        // MFMA col (= sample; valid < 4)
  const int quad = lane >> 4;

  // ---- phase-1 state: threads 0..127, thread = (oct o = t>>2, sample s = t&3)
  float mem3[8], cur3r[8];
  if (t < 128) {
    const int o = t >> 2, s = t & 3;
    const float* cp = cur3 + (size_t)(sb + s) * 256 + o * 8;
    float4 c0 = *(const float4*)cp;
    float4 c1 = *(const float4*)(cp + 4);
    cur3r[0] = c0.x; cur3r[1] = c0.y; cur3r[2] = c0.z; cur3r[3] = c0.w;
    cur3r[4] = c1.x; cur3r[5] = c1.y; cur3r[6] = c1.z; cur3r[7] = c1.w;
#pragma unroll
    for (int j = 0; j < 8; ++j) mem3[j] = 0.0f;
  }

  // ---- fc2 A-frags: A[m=j_local=lane&15][k=i=quad*8+jj], hi/lo exact split
  half8 a2h[8], a2l[8];
  {
    const float* wr = w2 + (size_t)(wave * 16 + n16) * 256 + quad * 8;
#pragma unroll
    for (int kt = 0; kt < 8; ++kt) {
      float4 u0 = *(const float4*)(wr + kt * 32);
      float4 u1 = *(const float4*)(wr + kt * 32 + 4);
      float wv[8] = {u0.x, u0.y, u0.z, u0.w, u1.x, u1.y, u1.z, u1.w};
#pragma unroll
      for (int e = 0; e < 8; ++e) {
        float hi = (float)(_Float16)wv[e];
        a2h[kt][e] = (_Float16)wv[e];
        a2l[kt][e] = (_Float16)(wv[e] - hi);
      }
    }
  }
  // bias for this lane's 4 rows (j = wave*16 + quad*4 + r)
  const float4 b2v = *(const float4*)(b2 + wave * 16 + quad * 4);
  float mem4[4] = {0.f, 0.f, 0.f, 0.f};

  // ---- fc3 A-frags (used by wave 0 only): A[m=cls][k=i], rows >=10 zero
  half8 a3h[4], a3l[4];
#pragma unroll
  for (int kt = 0; kt < 4; ++kt) { a3h[kt] = (half8){}; a3l[kt] = (half8){}; }
  if (n16 < 10) {
    const float* wr = w3 + (size_t)n16 * 128 + quad * 8;
#pragma unroll
    for (int kt = 0; kt < 4; ++kt) {
      float4 u0 = *(const float4*)(wr + kt * 32);
      float4 u1 = *(const float4*)(wr + kt * 32 + 4);
      float wv[8] = {u0.x, u0.y, u0.z, u0.w, u1.x, u1.y, u1.z, u1.w};
#pragma unroll
      for (int e = 0; e < 8; ++e) {
        float hi = (float)(_Float16)wv[e];
        a3h[kt][e] = (_Float16)wv[e];
        a3l[kt][e] = (_Float16)(wv[e] - hi);
      }
    }
  }
  float b3r[4];
#pragma unroll
  for (int r = 0; r < 4; ++r) {
    int cls = quad * 4 + r;
    b3r[r] = (cls < 10) ? b3[cls] : 0.0f;
  }
  float mem5[4] = {0.f, 0.f, 0.f, 0.f};

  __syncthreads();

  for (int step = 0; step < NSTEP; ++step) {
    // ---- layer 3: LIF + pack 8 spikes -> one b128 LDS write
    if (t < 128) {
      const int o = t >> 2, s = t & 3;
      half8 sv;
#pragma unroll
      for (int j = 0; j < 8; ++j) {
        mem3[j] = lif_update(mem3[j], cur3r[j]);
        sv[j] = (_Float16)((mem3[j] > 1.0f) ? 1.0f : 0.0f);
      }
      *(half8*)&spk3[o * 32 + s * 8] = sv;
    }
    __syncthreads();
    // ---- layer 4: MFMA D[j16 x s16] = W2 * spk3, all 8 waves (one n-tile each)
    {
      float4v acc0 = {0.f, 0.f, 0.f, 0.f}, acc1 = {0.f, 0.f, 0.f, 0.f};
#pragma unroll
      for (int kt = 0; kt < 8; ++kt) {
        half8 b = *(const half8*)&spk3[(kt * 4 + quad) * 32 + n16 * 8];
        acc0 = __builtin_amdgcn_mfma_f32_16x16x32_f16(a2h[kt], b, acc0, 0, 0, 0);
        acc1 = __builtin_amdgcn_mfma_f32_16x16x32_f16(a2l[kt], b, acc1, 0, 0, 0);
      }
      if (n16 < 4) {   // valid sample columns
        half4v pk;
#pragma unroll
        for (int r = 0; r < 4; ++r) {
          float cur4 = (acc0[r] + acc1[r]) + b2v[r];
          mem4[r] = lif_update(mem4[r], cur4);
          pk[r] = (_Float16)((mem4[r] > 1.0f) ? 1.0f : 0.0f);
        }
        // j0 = wave*16 + quad*4 -> oct = wave*2 + (quad>>1), off = (quad&1)*4
        *(half4v*)&spk4[(wave * 2 + (quad >> 1)) * 32 + n16 * 8 + (quad & 1) * 4] = pk;
      }
    }
    __syncthreads();
    // ---- layer 5: wave 0 MFMA D[cls16 x s16] = W3 * spk4
    if (wave == 0) {
      float4v c0 = {0.f, 0.f, 0.f, 0.f}, c1 = {0.f, 0.f, 0.f, 0.f};
#pragma unroll
      for (int kt = 0; kt < 4; ++kt) {
        half8 b = *(const half8*)&spk4[(kt * 4 + quad) * 32 + n16 * 8];
        c0 = __builtin_amdgcn_mfma_f32_16x16x32_f16(a3h[kt], b, c0, 0, 0, 0);
        c1 = __builtin_amdgcn_mfma_f32_16x16x32_f16(a3l[kt], b, c1, 0, 0, 0);
      }
#pragma unroll
      for (int r = 0; r < 4; ++r) {
        int cls = quad * 4 + r;
        float cur5 = (c0[r] + c1[r]) + b3r[r];
        mem5[r] = lif_update(mem5[r], cur5);
        if (n16 < 4 && cls < 10)
          out[(size_t)step * 10240 + (size_t)(sb + n16) * 10 + cls] =
              (mem5[r] > 1.0f) ? 1.0f : 0.0f;
      }
    }
    __syncthreads();
  }
}

// ---------------------------------------------------------------- launcher
extern "C" void kernel_launch(void* const* d_in, const int* in_sizes, int n_in,
                              void* d_out, int out_size, void* d_ws, size_t ws_size,
                              hipStream_t stream) {
  (void)in_sizes; (void)n_in; (void)out_size; (void)ws_size;
  const float* x   = (const float*)d_in[0];
  const float* w1c = (const float*)d_in[1];
  const float* b1c = (const float*)d_in[2];
  const float* w2c = (const float*)d_in[3];
  const float* b2c = (const float*)d_in[4];
  const float* fw1 = (const float*)d_in[5];
  const float* fb1 = (const float*)d_in[6];
  const float* fw2 = (const float*)d_in[7];
  const float* fb2 = (const float*)d_in[8];
  const float* fw3 = (const float*)d_in[9];
  const float* fb3 = (const float*)d_in[10];
  float* out = (float*)d_out;

  char* ws = (char*)d_ws;
  _Float16* c1    = (_Float16*)ws;                    // 32 MB (conv phase)
  float*    part  = (float*)ws;                       // 32 MB (fc1 phase, aliased)
  uint8_t*  xq    = (uint8_t*)(ws + (32u << 20));     //  8 MB
  float*    cur3  = (float*)(ws + (40u << 20));       //  1 MB
  _Float16* afrag = (_Float16*)(ws + (41u << 20));    // 72 KB

  k_prep<<<dim3(72), dim3(64), 0, stream>>>(w2c, afrag);
  k_conv1<<<dim3(1024), dim3(256), 0, stream>>>(x, w1c, b1c, c1);
  k_conv2<<<dim3(1024), dim3(256), 0, stream>>>(c1, afrag, b2c, xq);
  k_fc1<<<dim3(512), dim3(256), 0, stream>>>(xq, fw1, part);
  k_fc1_reduce<<<dim3(1024), dim3(256), 0, stream>>>(part, fb1, cur3);
  k_lif<<<dim3(256), dim3(512), 0, stream>>>(cur3, fw2, fb2, fw3, fb3, out);
}

// Round 5
// 204.288 us; speedup vs baseline: 2.0863x; 1.1922x over previous
//
#include <hip/hip_runtime.h>
#include <stdint.h>

// AudioSNN: conv1(1->32)+spike+pool -> conv2(32->64)+spike+pool -> fc1
// -> 25-step LIF (fc2, fc3).
// conv2, fc1, and the recurrent fc2/fc3 all run on MFMA: activations/spikes
// are exact small integers (exact fp16), weights use an exact 2-way fp16
// split (err ~2^-22; fp16 denormal lo-terms verified honored by MFMA,
// absmax 0 in R3/R4) -> fp32-faithful spike decisions.
//
// ws layout (region A aliased: c1 used by conv1/conv2, part by fc1 after):
//   A    : c1 fp16 [1024][32y][16x][32ch]  32 MB / part f32 [32][1024][256] 32 MB
//   xq   u8  [1024][8192]          @32M   8 MB
//   cur3 f32 [1024][256]           @40M   1 MB
//   afrag f16 [9][4][2][512]       @41M   72 KB  (conv2 A fragments hi/lo)
//   w1s  f16 [2][16][256][512]     @42M   8 MB   (fc1 A fragments hi/lo planes)

#define NSTEP 25

using half8   = __attribute__((ext_vector_type(8))) _Float16;
using half4v  = __attribute__((ext_vector_type(4))) _Float16;
using float4v = __attribute__((ext_vector_type(4))) float;

__device__ __forceinline__ float lif_update(float mem, float cur) {
#pragma clang fp contract(off)
  float reset = (mem > 1.0f) ? 1.0f : 0.0f;
  float m = 0.95f * mem;
  m = m + cur;
  m = m - reset;
  return m;
}

// ------------------------------------------------- conv2 A-fragment prep (split)
__global__ __launch_bounds__(64) void k_prep(const float* __restrict__ w2c,
                                             _Float16* __restrict__ afrag) {
  const int b = blockIdx.x;         // 72 = 9 taps x 4 mtiles x 2 splits
  const int tp = b >> 3;
  const int mt = (b & 7) >> 1;
  const int sp = b & 1;
  const int lane = threadIdx.x;
  const int m = lane & 15, quad = lane >> 4;
#pragma unroll
  for (int j = 0; j < 8; ++j) {
    int ch = quad * 8 + j;
    int oc = mt * 16 + m;
    float wv = w2c[(size_t)(oc * 32 + ch) * 9 + tp];
    float hi = (float)(_Float16)wv;
    _Float16 val = (sp == 0) ? (_Float16)wv : (_Float16)(wv - hi);
    afrag[(size_t)b * 512 + lane * 8 + j] = val;
  }
}

// ------------------------------------------------- fc1 A-fragment prep (split)
// w1s[sp][mt(16)][kcg(256)][lane(64)][j(8)] ; A[m=lane&15][k=quad*8+j].
// Writes are wave-contiguous 1 KB; reads are strided but L2-absorbed.
__global__ __launch_bounds__(256) void k_prep1(const float* __restrict__ w1,
                                               _Float16* __restrict__ w1s) {
  const int W = blockIdx.x * 4 + (threadIdx.x >> 6);  // 0..4095 = mt*256+kcg
  const int lane = threadIdx.x & 63;
  const int mt = W >> 8, kcg = W & 255;
  const int m = lane & 15, quad = lane >> 4;
  const float* src = w1 + (size_t)(mt * 16 + m) * 8192 + kcg * 32 + quad * 8;
  float4 u0 = *(const float4*)src;
  float4 u1 = *(const float4*)(src + 4);
  float wv[8] = {u0.x, u0.y, u0.z, u0.w, u1.x, u1.y, u1.z, u1.w};
  half8 hi, lo;
#pragma unroll
  for (int e = 0; e < 8; ++e) {
    float h = (float)(_Float16)wv[e];
    hi[e] = (_Float16)wv[e];
    lo[e] = (_Float16)(wv[e] - h);
  }
  _Float16* dst = w1s + ((size_t)W) * 512 + lane * 8;
  *(half8*)dst = hi;
  *(half8*)(dst + (size_t)16 * 256 * 512) = lo;   // lo plane at +4 MB
}

// ---------------------------------------------------------------- conv1 fused
// Output: fp16 pool-counts, layout [s][pos(512)][ch(32)] (channel-innermost).
__global__ __launch_bounds__(256) void k_conv1(const float* __restrict__ x,
                                               const float* __restrict__ w,
                                               const float* __restrict__ bias,
                                               _Float16* __restrict__ c1) {
  __shared__ float xin[66 * 34];   // 64x32 + SAME halo, zero padded
  __shared__ float wl[288];
  __shared__ float bl[32];
  const int t = threadIdx.x;
  const int s = blockIdx.x;

  for (int idx = t; idx < 66 * 34; idx += 256) xin[idx] = 0.0f;
  wl[t] = w[t];
  if (t < 32) { wl[256 + t] = w[256 + t]; bl[t] = bias[t]; }
  __syncthreads();

  const float* xs = x + (size_t)s * (64 * 32);
#pragma unroll
  for (int r = 0; r < 2; ++r) {
    int idx = t + r * 256;
    int y = idx >> 3, q = idx & 7;
    float4 v = *(const float4*)(xs + y * 32 + q * 4);
    float* dst = &xin[(y + 1) * 34 + q * 4 + 1];
    dst[0] = v.x; dst[1] = v.y; dst[2] = v.z; dst[3] = v.w;
  }
  __syncthreads();

  const int ch = t & 31;
  const int po = t >> 5;
  float wc[9];
#pragma unroll
  for (int i = 0; i < 9; ++i) wc[i] = wl[ch * 9 + i];
  const float bv = bl[ch];

  _Float16* c1s = c1 + (size_t)s * (512 * 32);
  for (int rr = 0; rr < 64; ++rr) {
    int pos = rr * 8 + po;
    int py = pos >> 4, px = pos & 15;
    float p[4][4];
#pragma unroll
    for (int rw = 0; rw < 4; ++rw) {
      float2 a = *(const float2*)&xin[(2 * py + rw) * 34 + 2 * px];
      float2 b = *(const float2*)&xin[(2 * py + rw) * 34 + 2 * px + 2];
      p[rw][0] = a.x; p[rw][1] = a.y; p[rw][2] = b.x; p[rw][3] = b.y;
    }
    int cnt = 0;
#pragma unroll
    for (int dy = 0; dy < 2; ++dy)
#pragma unroll
      for (int dx = 0; dx < 2; ++dx) {
        float acc = 0.0f;
#pragma unroll
        for (int ky = 0; ky < 3; ++ky)
#pragma unroll
          for (int kx = 0; kx < 3; ++kx)
            acc += wc[ky * 3 + kx] * p[dy + ky][dx + kx];
        float v = acc + bv;
        cnt += (v > 1.0f) ? 1 : 0;
      }
    c1s[pos * 32 + ch] = (_Float16)(float)cnt;
  }
}

// ---------------------------------------------------------------- conv2 (MFMA)
__global__ __launch_bounds__(256, 2) void k_conv2(const _Float16* __restrict__ c1,
                                                  const _Float16* __restrict__ afrag,
                                                  const float* __restrict__ bias,
                                                  uint8_t* __restrict__ xq) {
  __shared__ _Float16 cin[34 * 18 * 40];   // [row 34][col 18][ch pad 40]
  const int t = threadIdx.x;
  const int s = blockIdx.x;

  {
    half8* cp = (half8*)cin;
    half8 z = {};
    for (int idx = t; idx < 3060; idx += 256) cp[idx] = z;
  }
  __syncthreads();

  const _Float16* c1s = c1 + (size_t)s * (512 * 32);
#pragma unroll
  for (int i = 0; i < 8; ++i) {
    int g = t + i * 256;
    int y = g >> 6, r = g & 63, x = r >> 2, oct = r & 3;
    half8 v = *(const half8*)(c1s + (y * 16 + x) * 32 + oct * 8);
    *(half8*)&cin[((y + 1) * 18 + (x + 1)) * 40 + oct * 8] = v;
  }
  __syncthreads();

  const int lane = t & 63;
  const int wave = __builtin_amdgcn_readfirstlane(t >> 6);
  const int xlane = lane & 15, quad = lane >> 4;

  float4v acc[4][8];
#pragma unroll
  for (int mt = 0; mt < 4; ++mt)
#pragma unroll
    for (int nt = 0; nt < 8; ++nt) acc[mt][nt] = (float4v){0.f, 0.f, 0.f, 0.f};

  for (int ky = 0; ky < 3; ++ky)
    for (int kx = 0; kx < 3; ++kx) {
      const int tp = ky * 3 + kx;
      half8 a[4][2];
#pragma unroll
      for (int mt = 0; mt < 4; ++mt)
#pragma unroll
        for (int sp = 0; sp < 2; ++sp)
          a[mt][sp] = *(const half8*)(afrag +
                        ((size_t)((tp * 4 + mt) * 2 + sp)) * 512 + lane * 8);
#pragma unroll
      for (int nt = 0; nt < 8; ++nt) {
        int row = wave * 8 + nt + ky;
        int col = xlane + kx;
        half8 b = *(const half8*)&cin[(row * 18 + col) * 40 + quad * 8];
#pragma unroll
        for (int mt = 0; mt < 4; ++mt) {
          acc[mt][nt] = __builtin_amdgcn_mfma_f32_16x16x32_f16(a[mt][0], b,
                                                               acc[mt][nt], 0, 0, 0);
          acc[mt][nt] = __builtin_amdgcn_mfma_f32_16x16x32_f16(a[mt][1], b,
                                                               acc[mt][nt], 0, 0, 0);
        }
      }
    }

  float bw[4][4];
#pragma unroll
  for (int mt = 0; mt < 4; ++mt)
#pragma unroll
    for (int r = 0; r < 4; ++r) bw[mt][r] = bias[mt * 16 + quad * 4 + r];

  uint8_t* xqs = xq + (size_t)s * 8192;
  const int px = xlane >> 1;
  const bool writer = (xlane & 1) == 0;
#pragma unroll
  for (int mt = 0; mt < 4; ++mt)
#pragma unroll
    for (int ntp = 0; ntp < 4; ++ntp) {
      int py = wave * 4 + ntp;
#pragma unroll
      for (int r = 0; r < 4; ++r) {
        float v0 = 0.25f * acc[mt][2 * ntp + 0][r] + bw[mt][r];
        float v1 = 0.25f * acc[mt][2 * ntp + 1][r] + bw[mt][r];
        int c = ((v0 > 1.0f) ? 1 : 0) + ((v1 > 1.0f) ? 1 : 0);
        c += __shfl_xor(c, 1, 64);
        if (writer) {
          int oc = mt * 16 + quad * 4 + r;
          xqs[oc * 128 + py * 8 + px] = (uint8_t)c;
        }
      }
    }
}

// ---------------------------------------------------------------- fc1 (MFMA)
// Block = 64 samples x 256 outputs x K=256 slice. Grid 512 = 16 st x 32 kb.
// A streamed coalesced from w1s (L3-resident), B staged u8->fp16 in LDS.
__global__ __launch_bounds__(256, 2) void k_fc1(const uint8_t* __restrict__ xq,
                                                const _Float16* __restrict__ w1s,
                                                float* __restrict__ part) {
  __shared__ _Float16 bt[8 * 4 * 64 * 8];   // [kc][nt][lane][8] = 32 KB
  const int t = threadIdx.x;
  const int sblk = blockIdx.x >> 5;   // 16 sample tiles of 64
  const int kblk = blockIdx.x & 31;   // 32 K slices of 256
  const int sb = sblk * 64;

  {  // stage B: row = sb + t>>2, 64B chunk = t&3 (256B-contig per 4 lanes)
    const int row = t >> 2;
    const int seg = t & 3;
    const int nt = row >> 4, n16 = row & 15;
    const uint8_t* src = xq + (size_t)(sb + row) * 8192 + kblk * 256 + seg * 64;
#pragma unroll
    for (int q = 0; q < 4; ++q) {
      uint4 u = *(const uint4*)(src + q * 16);
      uint32_t wd[4] = {u.x, u.y, u.z, u.w};
#pragma unroll
      for (int g = 0; g < 2; ++g) {
        half8 h;
#pragma unroll
        for (int e = 0; e < 8; ++e) {
          uint32_t word = wd[g * 2 + (e >> 2)];
          h[e] = (_Float16)(unsigned short)((word >> ((e & 3) * 8)) & 0xffu);
        }
        int koff = seg * 64 + q * 16 + g * 8;        // 0..255
        int kc = koff >> 5, quad = (koff >> 3) & 3;
        *(half8*)&bt[(((kc * 4 + nt) * 64) + quad * 16 + n16) * 8] = h;
      }
    }
  }
  __syncthreads();

  const int lane = t & 63;
  const int wave = __builtin_amdgcn_readfirstlane(t >> 6);  // o-range wave*64

  float4v acc[4][4];
#pragma unroll
  for (int mt = 0; mt < 4; ++mt)
#pragma unroll
    for (int nt = 0; nt < 4; ++nt) acc[mt][nt] = (float4v){0.f, 0.f, 0.f, 0.f};

#pragma unroll
  for (int kc = 0; kc < 8; ++kc) {
    const int kcg = kblk * 8 + kc;
    half8 b[4];
#pragma unroll
    for (int nt = 0; nt < 4; ++nt)
      b[nt] = *(const half8*)&bt[((kc * 4 + nt) * 64 + lane) * 8];
#pragma unroll
    for (int mt = 0; mt < 4; ++mt) {
      const _Float16* ap = w1s + ((size_t)((wave * 4 + mt) * 256 + kcg)) * 512 + lane * 8;
      half8 ah = *(const half8*)ap;
      half8 al = *(const half8*)(ap + (size_t)16 * 256 * 512);
#pragma unroll
      for (int nt = 0; nt < 4; ++nt) {
        acc[mt][nt] = __builtin_amdgcn_mfma_f32_16x16x32_f16(ah, b[nt],
                                                             acc[mt][nt], 0, 0, 0);
        acc[mt][nt] = __builtin_amdgcn_mfma_f32_16x16x32_f16(al, b[nt],
                                                             acc[mt][nt], 0, 0, 0);
      }
    }
  }

  // epilogue: part[kblk][s][o] = 0.25*acc (counts -> counts/4), float4 stores
  const int n16 = lane & 15, quad = lane >> 4;
  float* pp = part + (size_t)kblk * (1024 * 256);
#pragma unroll
  for (int mt = 0; mt < 4; ++mt)
#pragma unroll
    for (int nt = 0; nt < 4; ++nt) {
      int s = sb + nt * 16 + n16;
      int ob = wave * 64 + mt * 16 + quad * 4;
      float4 v = {0.25f * acc[mt][nt][0], 0.25f * acc[mt][nt][1],
                  0.25f * acc[mt][nt][2], 0.25f * acc[mt][nt][3]};
      *(float4*)&pp[(size_t)s * 256 + ob] = v;
    }
}

__global__ __launch_bounds__(256) void k_fc1_reduce(const float* __restrict__ part,
                                                    const float* __restrict__ b1,
                                                    float* __restrict__ cur3) {
  int idx = blockIdx.x * 256 + threadIdx.x;
  int o = idx & 255;
  float s = 0.0f;
  for (int kb = 0; kb < 32; ++kb) s += part[(size_t)kb * (1024 * 256) + idx];
  cur3[idx] = s + b1[o];
}

// ---------------------------------------------------------------- LIF recurrence
__global__ __launch_bounds__(512, 2) void k_lif(const float* __restrict__ cur3,
                                                const float* __restrict__ w2,   // [128][256]
                                                const float* __restrict__ b2,
                                                const float* __restrict__ w3,   // [10][128]
                                                const float* __restrict__ b3,
                                                float* __restrict__ out) {
  __shared__ _Float16 spk3[1152];   // [oct32][s4][8] + pad
  __shared__ _Float16 spk4[640];    // [oct16][s4][8] + pad
  const int t = threadIdx.x;
  const int sb = blockIdx.x * 4;    // 4 samples/block, grid 256 = 1 block/CU
  const int lane = t & 63;
  const int wave = __builtin_amdgcn_readfirstlane(t >> 6);
  const int n16 = lane & 15;
  const int quad = lane >> 4;

  float mem3[8], cur3r[8];
  if (t < 128) {
    const int o = t >> 2, s = t & 3;
    const float* cp = cur3 + (size_t)(sb + s) * 256 + o * 8;
    float4 c0 = *(const float4*)cp;
    float4 c1 = *(const float4*)(cp + 4);
    cur3r[0] = c0.x; cur3r[1] = c0.y; cur3r[2] = c0.z; cur3r[3] = c0.w;
    cur3r[4] = c1.x; cur3r[5] = c1.y; cur3r[6] = c1.z; cur3r[7] = c1.w;
#pragma unroll
    for (int j = 0; j < 8; ++j) mem3[j] = 0.0f;
  }

  half8 a2h[8], a2l[8];
  {
    const float* wr = w2 + (size_t)(wave * 16 + n16) * 256 + quad * 8;
#pragma unroll
    for (int kt = 0; kt < 8; ++kt) {
      float4 u0 = *(const float4*)(wr + kt * 32);
      float4 u1 = *(const float4*)(wr + kt * 32 + 4);
      float wv[8] = {u0.x, u0.y, u0.z, u0.w, u1.x, u1.y, u1.z, u1.w};
#pragma unroll
      for (int e = 0; e < 8; ++e) {
        float hi = (float)(_Float16)wv[e];
        a2h[kt][e] = (_Float16)wv[e];
        a2l[kt][e] = (_Float16)(wv[e] - hi);
      }
    }
  }
  const float4 b2v = *(const float4*)(b2 + wave * 16 + quad * 4);
  float mem4[4] = {0.f, 0.f, 0.f, 0.f};

  half8 a3h[4], a3l[4];
#pragma unroll
  for (int kt = 0; kt < 4; ++kt) { a3h[kt] = (half8){}; a3l[kt] = (half8){}; }
  if (n16 < 10) {
    const float* wr = w3 + (size_t)n16 * 128 + quad * 8;
#pragma unroll
    for (int kt = 0; kt < 4; ++kt) {
      float4 u0 = *(const float4*)(wr + kt * 32);
      float4 u1 = *(const float4*)(wr + kt * 32 + 4);
      float wv[8] = {u0.x, u0.y, u0.z, u0.w, u1.x, u1.y, u1.z, u1.w};
#pragma unroll
      for (int e = 0; e < 8; ++e) {
        float hi = (float)(_Float16)wv[e];
        a3h[kt][e] = (_Float16)wv[e];
        a3l[kt][e] = (_Float16)(wv[e] - hi);
      }
    }
  }
  float b3r[4];
#pragma unroll
  for (int r = 0; r < 4; ++r) {
    int cls = quad * 4 + r;
    b3r[r] = (cls < 10) ? b3[cls] : 0.0f;
  }
  float mem5[4] = {0.f, 0.f, 0.f, 0.f};

  __syncthreads();

  for (int step = 0; step < NSTEP; ++step) {
    if (t < 128) {
      const int o = t >> 2, s = t & 3;
      half8 sv;
#pragma unroll
      for (int j = 0; j < 8; ++j) {
        mem3[j] = lif_update(mem3[j], cur3r[j]);
        sv[j] = (_Float16)((mem3[j] > 1.0f) ? 1.0f : 0.0f);
      }
      *(half8*)&spk3[o * 32 + s * 8] = sv;
    }
    __syncthreads();
    {
      float4v acc0 = {0.f, 0.f, 0.f, 0.f}, acc1 = {0.f, 0.f, 0.f, 0.f};
#pragma unroll
      for (int kt = 0; kt < 8; ++kt) {
        half8 b = *(const half8*)&spk3[(kt * 4 + quad) * 32 + n16 * 8];
        acc0 = __builtin_amdgcn_mfma_f32_16x16x32_f16(a2h[kt], b, acc0, 0, 0, 0);
        acc1 = __builtin_amdgcn_mfma_f32_16x16x32_f16(a2l[kt], b, acc1, 0, 0, 0);
      }
      if (n16 < 4) {
        half4v pk;
#pragma unroll
        for (int r = 0; r < 4; ++r) {
          float cur4 = (acc0[r] + acc1[r]) + b2v[r];
          mem4[r] = lif_update(mem4[r], cur4);
          pk[r] = (_Float16)((mem4[r] > 1.0f) ? 1.0f : 0.0f);
        }
        *(half4v*)&spk4[(wave * 2 + (quad >> 1)) * 32 + n16 * 8 + (quad & 1) * 4] = pk;
      }
    }
    __syncthreads();
    if (wave == 0) {
      float4v c0 = {0.f, 0.f, 0.f, 0.f}, c1 = {0.f, 0.f, 0.f, 0.f};
#pragma unroll
      for (int kt = 0; kt < 4; ++kt) {
        half8 b = *(const half8*)&spk4[(kt * 4 + quad) * 32 + n16 * 8];
        c0 = __builtin_amdgcn_mfma_f32_16x16x32_f16(a3h[kt], b, c0, 0, 0, 0);
        c1 = __builtin_amdgcn_mfma_f32_16x16x32_f16(a3l[kt], b, c1, 0, 0, 0);
      }
#pragma unroll
      for (int r = 0; r < 4; ++r) {
        int cls = quad * 4 + r;
        float cur5 = (c0[r] + c1[r]) + b3r[r];
        mem5[r] = lif_update(mem5[r], cur5);
        if (n16 < 4 && cls < 10)
          out[(size_t)step * 10240 + (size_t)(sb + n16) * 10 + cls] =
              (mem5[r] > 1.0f) ? 1.0f : 0.0f;
      }
    }
    __syncthreads();
  }
}

// ---------------------------------------------------------------- launcher
extern "C" void kernel_launch(void* const* d_in, const int* in_sizes, int n_in,
                              void* d_out, int out_size, void* d_ws, size_t ws_size,
                              hipStream_t stream) {
  (void)in_sizes; (void)n_in; (void)out_size; (void)ws_size;
  const float* x   = (const float*)d_in[0];
  const float* w1c = (const float*)d_in[1];
  const float* b1c = (const float*)d_in[2];
  const float* w2c = (const float*)d_in[3];
  const float* b2c = (const float*)d_in[4];
  const float* fw1 = (const float*)d_in[5];
  const float* fb1 = (const float*)d_in[6];
  const float* fw2 = (const float*)d_in[7];
  const float* fb2 = (const float*)d_in[8];
  const float* fw3 = (const float*)d_in[9];
  const float* fb3 = (const float*)d_in[10];
  float* out = (float*)d_out;

  char* ws = (char*)d_ws;
  _Float16* c1    = (_Float16*)ws;                    // 32 MB (conv phase)
  float*    part  = (float*)ws;                       // 32 MB (fc1 phase, aliased)
  uint8_t*  xq    = (uint8_t*)(ws + (32u << 20));     //  8 MB
  float*    cur3  = (float*)(ws + (40u << 20));       //  1 MB
  _Float16* afrag = (_Float16*)(ws + (41u << 20));    // 72 KB
  _Float16* w1s   = (_Float16*)(ws + (42u << 20));    //  8 MB

  k_prep<<<dim3(72), dim3(64), 0, stream>>>(w2c, afrag);
  k_prep1<<<dim3(1024), dim3(256), 0, stream>>>(fw1, w1s);
  k_conv1<<<dim3(1024), dim3(256), 0, stream>>>(x, w1c, b1c, c1);
  k_conv2<<<dim3(1024), dim3(256), 0, stream>>>(c1, afrag, b2c, xq);
  k_fc1<<<dim3(512), dim3(256), 0, stream>>>(xq, w1s, part);
  k_fc1_reduce<<<dim3(1024), dim3(256), 0, stream>>>(part, fb1, cur3);
  k_lif<<<dim3(256), dim3(512), 0, stream>>>(cur3, fw2, fb2, fw3, fb3, out);
}

// Round 6
// 191.977 us; speedup vs baseline: 2.2201x; 1.0641x over previous
//
#include <hip/hip_runtime.h>
#include <stdint.h>

// AudioSNN: conv1(1->32)+spike+pool -> conv2(32->64)+spike+pool -> fc1
// -> 25-step LIF (fc2, fc3).
// conv2, fc1, fc2/fc3 all run on MFMA: activations/spikes are exact small
// integers (exact fp16), weights use an exact 2-way fp16 split (err ~2^-22;
// fp16 denormal lo-terms verified honored by MFMA, absmax 0 in R3/R4/R5).
// R6: conv1+conv2 fused (c1 lives in LDS), fc1-reduce fused into k_lif,
// preps merged -> 4 launches total.
//
// ws layout:
//   part f32 [32][1024][256]       @0     32 MB
//   xq   u8  [1024][8192]          @32M    8 MB
//   afrag f16 [9][4][2][512]       @41M   72 KB  (conv2 A fragments hi/lo)
//   w1s  f16 [2][16][256][512]     @42M    8 MB  (fc1 A fragments hi/lo planes)

#define NSTEP 25

using half8   = __attribute__((ext_vector_type(8))) _Float16;
using half4v  = __attribute__((ext_vector_type(4))) _Float16;
using float4v = __attribute__((ext_vector_type(4))) float;

__device__ __forceinline__ float lif_update(float mem, float cur) {
#pragma clang fp contract(off)
  float reset = (mem > 1.0f) ? 1.0f : 0.0f;
  float m = 0.95f * mem;
  m = m + cur;
  m = m - reset;
  return m;
}

// ------------------------------------------------- weight prep (both fragments)
// blocks 0..71: conv2 afrag (9 taps x 4 mtiles x 2 splits, 64 active threads)
// blocks 72..1095: fc1 w1s (4 fragment-groups per block)
__global__ __launch_bounds__(256) void k_prep(const float* __restrict__ w2c,
                                              const float* __restrict__ w1,
                                              _Float16* __restrict__ afrag,
                                              _Float16* __restrict__ w1s) {
  const int b = blockIdx.x;
  const int t = threadIdx.x;
  if (b < 72) {
    if (t < 64) {
      const int tp = b >> 3;
      const int mt = (b & 7) >> 1;
      const int sp = b & 1;
      const int m = t & 15, quad = t >> 4;
#pragma unroll
      for (int j = 0; j < 8; ++j) {
        int ch = quad * 8 + j;
        int oc = mt * 16 + m;
        float wv = w2c[(size_t)(oc * 32 + ch) * 9 + tp];
        float hi = (float)(_Float16)wv;
        _Float16 val = (sp == 0) ? (_Float16)wv : (_Float16)(wv - hi);
        afrag[(size_t)b * 512 + t * 8 + j] = val;
      }
    }
    return;
  }
  const int W = (b - 72) * 4 + (t >> 6);  // 0..4095 = mt*256+kcg
  const int lane = t & 63;
  const int mt = W >> 8, kcg = W & 255;
  const int m = lane & 15, quad = lane >> 4;
  const float* src = w1 + (size_t)(mt * 16 + m) * 8192 + kcg * 32 + quad * 8;
  float4 u0 = *(const float4*)src;
  float4 u1 = *(const float4*)(src + 4);
  float wv[8] = {u0.x, u0.y, u0.z, u0.w, u1.x, u1.y, u1.z, u1.w};
  half8 hi, lo;
#pragma unroll
  for (int e = 0; e < 8; ++e) {
    float h = (float)(_Float16)wv[e];
    hi[e] = (_Float16)wv[e];
    lo[e] = (_Float16)(wv[e] - h);
  }
  _Float16* dst = w1s + ((size_t)W) * 512 + lane * 8;
  *(half8*)dst = hi;
  *(half8*)(dst + (size_t)16 * 256 * 512) = lo;   // lo plane at +4 MB
}

// -------------------------------------------- fused conv1+conv2 (one sample)
// Phase 1 (VALU): conv1+spike+pool -> integer counts, written into cin (LDS).
// Phase 2 (MFMA): conv2 implicit GEMM from cin, spike+pool -> xq u8 counts.
__global__ __launch_bounds__(256, 2) void k_conv(const float* __restrict__ x,
                                                 const float* __restrict__ w1c,
                                                 const float* __restrict__ b1c,
                                                 const _Float16* __restrict__ afrag,
                                                 const float* __restrict__ b2c,
                                                 uint8_t* __restrict__ xq) {
  __shared__ _Float16 cin[34 * 18 * 40];  // [row 34][col 18][ch pad 40] 48960 B
  __shared__ float xin[66 * 34];          // conv1 input + halo
  __shared__ float wl[288];
  __shared__ float bl[32];
  const int t = threadIdx.x;
  const int s = blockIdx.x;

  {  // zero cin (covers halos), stage conv1 weights + input
    half8* cp = (half8*)cin;
    half8 z = {};
    for (int idx = t; idx < 3060; idx += 256) cp[idx] = z;
  }
  for (int idx = t; idx < 66 * 34; idx += 256) xin[idx] = 0.0f;
  wl[t] = w1c[t];
  if (t < 32) { wl[256 + t] = w1c[256 + t]; bl[t] = b1c[t]; }
  __syncthreads();

  const float* xs = x + (size_t)s * (64 * 32);
#pragma unroll
  for (int r = 0; r < 2; ++r) {
    int idx = t + r * 256;
    int y = idx >> 3, q = idx & 7;
    float4 v = *(const float4*)(xs + y * 32 + q * 4);
    float* dst = &xin[(y + 1) * 34 + q * 4 + 1];
    dst[0] = v.x; dst[1] = v.y; dst[2] = v.z; dst[3] = v.w;
  }
  __syncthreads();

  // ---- phase 1: conv1 (LDS reads are wave-broadcast; writes 2-way = free)
  {
    const int ch = t & 31;
    const int po = t >> 5;
    float wc[9];
#pragma unroll
    for (int i = 0; i < 9; ++i) wc[i] = wl[ch * 9 + i];
    const float bv = bl[ch];
    for (int rr = 0; rr < 64; ++rr) {
      int pos = rr * 8 + po;
      int py = pos >> 4, px = pos & 15;
      float p[4][4];
#pragma unroll
      for (int rw = 0; rw < 4; ++rw) {
        float2 a = *(const float2*)&xin[(2 * py + rw) * 34 + 2 * px];
        float2 b = *(const float2*)&xin[(2 * py + rw) * 34 + 2 * px + 2];
        p[rw][0] = a.x; p[rw][1] = a.y; p[rw][2] = b.x; p[rw][3] = b.y;
      }
      int cnt = 0;
#pragma unroll
      for (int dy = 0; dy < 2; ++dy)
#pragma unroll
        for (int dx = 0; dx < 2; ++dx) {
          float acc = 0.0f;
#pragma unroll
          for (int ky = 0; ky < 3; ++ky)
#pragma unroll
            for (int kx = 0; kx < 3; ++kx)
              acc += wc[ky * 3 + kx] * p[dy + ky][dx + kx];
          float v = acc + bv;
          cnt += (v > 1.0f) ? 1 : 0;
        }
      cin[((py + 1) * 18 + (px + 1)) * 40 + ch] = (_Float16)(float)cnt;
    }
  }
  __syncthreads();

  // ---- phase 2: conv2 MFMA (M=64 oc, N=512 pos, K=32 ch per tap x 9)
  const int lane = t & 63;
  const int wave = __builtin_amdgcn_readfirstlane(t >> 6);
  const int xlane = lane & 15, quad = lane >> 4;

  float4v acc[4][8];
#pragma unroll
  for (int mt = 0; mt < 4; ++mt)
#pragma unroll
    for (int nt = 0; nt < 8; ++nt) acc[mt][nt] = (float4v){0.f, 0.f, 0.f, 0.f};

  for (int ky = 0; ky < 3; ++ky)
    for (int kx = 0; kx < 3; ++kx) {
      const int tp = ky * 3 + kx;
      half8 a[4][2];
#pragma unroll
      for (int mt = 0; mt < 4; ++mt)
#pragma unroll
        for (int sp = 0; sp < 2; ++sp)
          a[mt][sp] = *(const half8*)(afrag +
                        ((size_t)((tp * 4 + mt) * 2 + sp)) * 512 + lane * 8);
#pragma unroll
      for (int nt = 0; nt < 8; ++nt) {
        int row = wave * 8 + nt + ky;
        int col = xlane + kx;
        half8 b = *(const half8*)&cin[(row * 18 + col) * 40 + quad * 8];
#pragma unroll
        for (int mt = 0; mt < 4; ++mt) {
          acc[mt][nt] = __builtin_amdgcn_mfma_f32_16x16x32_f16(a[mt][0], b,
                                                               acc[mt][nt], 0, 0, 0);
          acc[mt][nt] = __builtin_amdgcn_mfma_f32_16x16x32_f16(a[mt][1], b,
                                                               acc[mt][nt], 0, 0, 0);
        }
      }
    }

  float bw[4][4];
#pragma unroll
  for (int mt = 0; mt < 4; ++mt)
#pragma unroll
    for (int r = 0; r < 4; ++r) bw[mt][r] = b2c[mt * 16 + quad * 4 + r];

  uint8_t* xqs = xq + (size_t)s * 8192;
  const int px = xlane >> 1;
  const bool writer = (xlane & 1) == 0;
#pragma unroll
  for (int mt = 0; mt < 4; ++mt)
#pragma unroll
    for (int ntp = 0; ntp < 4; ++ntp) {
      int py = wave * 4 + ntp;
#pragma unroll
      for (int r = 0; r < 4; ++r) {
        float v0 = 0.25f * acc[mt][2 * ntp + 0][r] + bw[mt][r];
        float v1 = 0.25f * acc[mt][2 * ntp + 1][r] + bw[mt][r];
        int c = ((v0 > 1.0f) ? 1 : 0) + ((v1 > 1.0f) ? 1 : 0);
        c += __shfl_xor(c, 1, 64);
        if (writer) {
          int oc = mt * 16 + quad * 4 + r;
          xqs[oc * 128 + py * 8 + px] = (uint8_t)c;
        }
      }
    }
}

// ---------------------------------------------------------------- fc1 (MFMA)
__global__ __launch_bounds__(256, 2) void k_fc1(const uint8_t* __restrict__ xq,
                                                const _Float16* __restrict__ w1s,
                                                float* __restrict__ part) {
  __shared__ _Float16 bt[8 * 4 * 64 * 8];   // [kc][nt][lane][8] = 32 KB
  const int t = threadIdx.x;
  const int sblk = blockIdx.x >> 5;   // 16 sample tiles of 64
  const int kblk = blockIdx.x & 31;   // 32 K slices of 256
  const int sb = sblk * 64;

  {  // stage B: u8 counts -> fp16, frag-ready
    const int row = t >> 2;
    const int seg = t & 3;
    const int nt = row >> 4, n16 = row & 15;
    const uint8_t* src = xq + (size_t)(sb + row) * 8192 + kblk * 256 + seg * 64;
#pragma unroll
    for (int q = 0; q < 4; ++q) {
      uint4 u = *(const uint4*)(src + q * 16);
      uint32_t wd[4] = {u.x, u.y, u.z, u.w};
#pragma unroll
      for (int g = 0; g < 2; ++g) {
        half8 h;
#pragma unroll
        for (int e = 0; e < 8; ++e) {
          uint32_t word = wd[g * 2 + (e >> 2)];
          h[e] = (_Float16)(unsigned short)((word >> ((e & 3) * 8)) & 0xffu);
        }
        int koff = seg * 64 + q * 16 + g * 8;
        int kc = koff >> 5, quad = (koff >> 3) & 3;
        *(half8*)&bt[(((kc * 4 + nt) * 64) + quad * 16 + n16) * 8] = h;
      }
    }
  }
  __syncthreads();

  const int lane = t & 63;
  const int wave = __builtin_amdgcn_readfirstlane(t >> 6);

  float4v acc[4][4];
#pragma unroll
  for (int mt = 0; mt < 4; ++mt)
#pragma unroll
    for (int nt = 0; nt < 4; ++nt) acc[mt][nt] = (float4v){0.f, 0.f, 0.f, 0.f};

#pragma unroll
  for (int kc = 0; kc < 8; ++kc) {
    const int kcg = kblk * 8 + kc;
    half8 b[4];
#pragma unroll
    for (int nt = 0; nt < 4; ++nt)
      b[nt] = *(const half8*)&bt[((kc * 4 + nt) * 64 + lane) * 8];
#pragma unroll
    for (int mt = 0; mt < 4; ++mt) {
      const _Float16* ap = w1s + ((size_t)((wave * 4 + mt) * 256 + kcg)) * 512 + lane * 8;
      half8 ah = *(const half8*)ap;
      half8 al = *(const half8*)(ap + (size_t)16 * 256 * 512);
#pragma unroll
      for (int nt = 0; nt < 4; ++nt) {
        acc[mt][nt] = __builtin_amdgcn_mfma_f32_16x16x32_f16(ah, b[nt],
                                                             acc[mt][nt], 0, 0, 0);
        acc[mt][nt] = __builtin_amdgcn_mfma_f32_16x16x32_f16(al, b[nt],
                                                             acc[mt][nt], 0, 0, 0);
      }
    }
  }

  const int n16 = lane & 15, quad = lane >> 4;
  float* pp = part + (size_t)kblk * (1024 * 256);
#pragma unroll
  for (int mt = 0; mt < 4; ++mt)
#pragma unroll
    for (int nt = 0; nt < 4; ++nt) {
      int s = sb + nt * 16 + n16;
      int ob = wave * 64 + mt * 16 + quad * 4;
      float4 v = {0.25f * acc[mt][nt][0], 0.25f * acc[mt][nt][1],
                  0.25f * acc[mt][nt][2], 0.25f * acc[mt][nt][3]};
      *(float4*)&pp[(size_t)s * 256 + ob] = v;
    }
}

// ---------------------------------------------------------------- LIF recurrence
// Now also performs the fc1 K-split reduction (part -> cur3, in LDS).
__global__ __launch_bounds__(512, 2) void k_lif(const float* __restrict__ part,
                                                const float* __restrict__ b1,
                                                const float* __restrict__ w2,   // [128][256]
                                                const float* __restrict__ b2,
                                                const float* __restrict__ w3,   // [10][128]
                                                const float* __restrict__ b3,
                                                float* __restrict__ out) {
  __shared__ float cur3l[1024];     // [s4][o256]
  __shared__ _Float16 spk3[1152];   // [oct32][s4][8] + pad
  __shared__ _Float16 spk4[640];    // [oct16][s4][8] + pad
  const int t = threadIdx.x;
  const int sb = blockIdx.x * 4;    // 4 samples/block, grid 256 = 1 block/CU
  const int lane = t & 63;
  const int wave = __builtin_amdgcn_readfirstlane(t >> 6);
  const int n16 = lane & 15;
  const int quad = lane >> 4;

  // ---- fc1 reduce: deterministic kb-order sum + bias-last (same as before)
#pragma unroll
  for (int r = 0; r < 2; ++r) {
    int v = t + r * 512;            // = s*256 + o
    int s = v >> 8, o = v & 255;
    float sum = 0.0f;
    for (int kb = 0; kb < 32; ++kb)
      sum += part[(size_t)kb * (1024 * 256) + (size_t)(sb + s) * 256 + o];
    cur3l[v] = sum + b1[o];
  }

  // ---- fc2 A-frags: A[m=lane&15][k=quad*8+jj], hi/lo exact split
  half8 a2h[8], a2l[8];
  {
    const float* wr = w2 + (size_t)(wave * 16 + n16) * 256 + quad * 8;
#pragma unroll
    for (int kt = 0; kt < 8; ++kt) {
      float4 u0 = *(const float4*)(wr + kt * 32);
      float4 u1 = *(const float4*)(wr + kt * 32 + 4);
      float wv[8] = {u0.x, u0.y, u0.z, u0.w, u1.x, u1.y, u1.z, u1.w};
#pragma unroll
      for (int e = 0; e < 8; ++e) {
        float hi = (float)(_Float16)wv[e];
        a2h[kt][e] = (_Float16)wv[e];
        a2l[kt][e] = (_Float16)(wv[e] - hi);
      }
    }
  }
  const float4 b2v = *(const float4*)(b2 + wave * 16 + quad * 4);
  float mem4[4] = {0.f, 0.f, 0.f, 0.f};

  // ---- fc3 A-frags (wave 0), rows >= 10 zero
  half8 a3h[4], a3l[4];
#pragma unroll
  for (int kt = 0; kt < 4; ++kt) { a3h[kt] = (half8){}; a3l[kt] = (half8){}; }
  if (n16 < 10) {
    const float* wr = w3 + (size_t)n16 * 128 + quad * 8;
#pragma unroll
    for (int kt = 0; kt < 4; ++kt) {
      float4 u0 = *(const float4*)(wr + kt * 32);
      float4 u1 = *(const float4*)(wr + kt * 32 + 4);
      float wv[8] = {u0.x, u0.y, u0.z, u0.w, u1.x, u1.y, u1.z, u1.w};
#pragma unroll
      for (int e = 0; e < 8; ++e) {
        float hi = (float)(_Float16)wv[e];
        a3h[kt][e] = (_Float16)wv[e];
        a3l[kt][e] = (_Float16)(wv[e] - hi);
      }
    }
  }
  float b3r[4];
#pragma unroll
  for (int r = 0; r < 4; ++r) {
    int cls = quad * 4 + r;
    b3r[r] = (cls < 10) ? b3[cls] : 0.0f;
  }
  float mem5[4] = {0.f, 0.f, 0.f, 0.f};

  __syncthreads();

  // ---- phase-1 state: threads 0..127, thread = (oct o = t>>2, sample s = t&3)
  float mem3[8], cur3r[8];
  if (t < 128) {
    const int o = t >> 2, s = t & 3;
    const float* cp = &cur3l[s * 256 + o * 8];
    float4 c0 = *(const float4*)cp;
    float4 c1 = *(const float4*)(cp + 4);
    cur3r[0] = c0.x; cur3r[1] = c0.y; cur3r[2] = c0.z; cur3r[3] = c0.w;
    cur3r[4] = c1.x; cur3r[5] = c1.y; cur3r[6] = c1.z; cur3r[7] = c1.w;
#pragma unroll
    for (int j = 0; j < 8; ++j) mem3[j] = 0.0f;
  }

  for (int step = 0; step < NSTEP; ++step) {
    if (t < 128) {
      const int o = t >> 2, s = t & 3;
      half8 sv;
#pragma unroll
      for (int j = 0; j < 8; ++j) {
        mem3[j] = lif_update(mem3[j], cur3r[j]);
        sv[j] = (_Float16)((mem3[j] > 1.0f) ? 1.0f : 0.0f);
      }
      *(half8*)&spk3[o * 32 + s * 8] = sv;
    }
    __syncthreads();
    {
      float4v acc0 = {0.f, 0.f, 0.f, 0.f}, acc1 = {0.f, 0.f, 0.f, 0.f};
#pragma unroll
      for (int kt = 0; kt < 8; ++kt) {
        half8 b = *(const half8*)&spk3[(kt * 4 + quad) * 32 + n16 * 8];
        acc0 = __builtin_amdgcn_mfma_f32_16x16x32_f16(a2h[kt], b, acc0, 0, 0, 0);
        acc1 = __builtin_amdgcn_mfma_f32_16x16x32_f16(a2l[kt], b, acc1, 0, 0, 0);
      }
      if (n16 < 4) {
        half4v pk;
#pragma unroll
        for (int r = 0; r < 4; ++r) {
          float cur4 = (acc0[r] + acc1[r]) + b2v[r];
          mem4[r] = lif_update(mem4[r], cur4);
          pk[r] = (_Float16)((mem4[r] > 1.0f) ? 1.0f : 0.0f);
        }
        *(half4v*)&spk4[(wave * 2 + (quad >> 1)) * 32 + n16 * 8 + (quad & 1) * 4] = pk;
      }
    }
    __syncthreads();
    if (wave == 0) {
      float4v c0 = {0.f, 0.f, 0.f, 0.f}, c1 = {0.f, 0.f, 0.f, 0.f};
#pragma unroll
      for (int kt = 0; kt < 4; ++kt) {
        half8 b = *(const half8*)&spk4[(kt * 4 + quad) * 32 + n16 * 8];
        c0 = __builtin_amdgcn_mfma_f32_16x16x32_f16(a3h[kt], b, c0, 0, 0, 0);
        c1 = __builtin_amdgcn_mfma_f32_16x16x32_f16(a3l[kt], b, c1, 0, 0, 0);
      }
#pragma unroll
      for (int r = 0; r < 4; ++r) {
        int cls = quad * 4 + r;
        float cur5 = (c0[r] + c1[r]) + b3r[r];
        mem5[r] = lif_update(mem5[r], cur5);
        if (n16 < 4 && cls < 10)
          out[(size_t)step * 10240 + (size_t)(sb + n16) * 10 + cls] =
              (mem5[r] > 1.0f) ? 1.0f : 0.0f;
      }
    }
    __syncthreads();
  }
}

// ---------------------------------------------------------------- launcher
extern "C" void kernel_launch(void* const* d_in, const int* in_sizes, int n_in,
                              void* d_out, int out_size, void* d_ws, size_t ws_size,
                              hipStream_t stream) {
  (void)in_sizes; (void)n_in; (void)out_size; (void)ws_size;
  const float* x   = (const float*)d_in[0];
  const float* w1c = (const float*)d_in[1];
  const float* b1c = (const float*)d_in[2];
  const float* w2c = (const float*)d_in[3];
  const float* b2c = (const float*)d_in[4];
  const float* fw1 = (const float*)d_in[5];
  const float* fb1 = (const float*)d_in[6];
  const float* fw2 = (const float*)d_in[7];
  const float* fb2 = (const float*)d_in[8];
  const float* fw3 = (const float*)d_in[9];
  const float* fb3 = (const float*)d_in[10];
  float* out = (float*)d_out;

  char* ws = (char*)d_ws;
  float*    part  = (float*)ws;                       // 32 MB
  uint8_t*  xq    = (uint8_t*)(ws + (32u << 20));     //  8 MB
  _Float16* afrag = (_Float16*)(ws + (41u << 20));    // 72 KB
  _Float16* w1s   = (_Float16*)(ws + (42u << 20));    //  8 MB

  k_prep<<<dim3(1096), dim3(256), 0, stream>>>(w2c, fw1, afrag, w1s);
  k_conv<<<dim3(1024), dim3(256), 0, stream>>>(x, w1c, b1c, afrag, b2c, xq);
  k_fc1<<<dim3(512), dim3(256), 0, stream>>>(xq, w1s, part);
  k_lif<<<dim3(256), dim3(512), 0, stream>>>(part, fb1, fw2, fb2, fw3, fb3, out);
}